// Round 2
// baseline (3064.249 us; speedup 1.0000x reference)
//
#include <hip/hip_runtime.h>

// ---------------------------------------------------------------------------
// HAN forward on MI355X.
// S=16 sents, B=32 batch, T=64 tokens, E=H=256, 2H=512, NC=50, V=50000.
// Pipeline:
//   k_prep          : bf16-convert + fragment-swizzle all weight matrices
//   k_gru_word      : 32 WGs (sentence x dir), fused [e|h] GEMM, h in regs
//   k_attn_score    : squish=tanh(out@W+b) . proj  -> scores   (word + sent)
//   k_word_pool     : softmax over T + weighted sum -> s[S,B,512]
//   k_sgih          : s @ sg_Wih^T (+bih)           -> xp_sent
//   k_gru_sent      : 2 WGs, 16 steps
//   k_sent_pool_fin : softmax over S + pool + final linear -> logits
// All GEMMs: bf16 MFMA 16x16x32 (BUILTIN — inline asm removed: asm MFMA is
// opaque to the hazard recognizer, so MFMA->VALU RAW wait-states were not
// guaranteed), fp32 accumulate.
// ---------------------------------------------------------------------------

typedef float  f32x4  __attribute__((ext_vector_type(4)));
typedef int    i32x4  __attribute__((ext_vector_type(4)));
typedef __bf16 bf16x8 __attribute__((ext_vector_type(8)));

#define DEVINL static __device__ __forceinline__

DEVINL unsigned short f2bf(float f) {          // RNE float->bf16
    unsigned int x = __builtin_bit_cast(unsigned int, f);
    x = x + 0x7fffu + ((x >> 16) & 1u);
    return (unsigned short)(x >> 16);
}
DEVINL float bf2f(unsigned short u) {
    unsigned int x = ((unsigned int)u) << 16;
    return __builtin_bit_cast(float, x);
}
DEVINL float sigm(float x) { return __builtin_amdgcn_rcpf(1.f + __expf(-x)); }
DEVINL float tanh_(float x) {
    x = fminf(fmaxf(x, -20.f), 20.f);
    float e = __expf(-2.f * x);
    return (1.f - e) * __builtin_amdgcn_rcpf(1.f + e);
}
DEVINL void mfma16(f32x4& acc, i32x4 a, i32x4 b) {
    acc = __builtin_amdgcn_mfma_f32_16x16x32_bf16(
        __builtin_bit_cast(bf16x8, a), __builtin_bit_cast(bf16x8, b), acc, 0, 0, 0);
}
DEVINL f32x4 zero4() { f32x4 v = {0.f, 0.f, 0.f, 0.f}; return v; }

// ---- workspace layout (bytes, all 256-aligned) ----------------------------
#define O_WPWF    ((size_t)0)         // word comb fwd  [1024n][512k] bf16 frag
#define O_WPWB    ((size_t)1048576)
#define O_WPSGIH  ((size_t)2097152)   // sent Wih cat   [1536n][512k]
#define O_WPSHHF  ((size_t)3670016)   // sent Whh fwd   [768n][256k]
#define O_WPSHHB  ((size_t)4063232)
#define O_WPWW    ((size_t)4456448)   // word_W^T       [512n][512k]
#define O_WPSW    ((size_t)4980736)   // sent_W^T
#define O_BIASWF  ((size_t)5505024)   // word bias comb [4][256] f32
#define O_BIASWB  ((size_t)5509120)
#define O_BIHCAT  ((size_t)5513216)   // sent bih cat [1536] f32
#define O_WOUT    ((size_t)5519360)   // word_out bf16 A-frag, rows 32768 x 512
#define O_SCORESW ((size_t)39073792)  // word scores f32 [32768]
#define O_SSFRAG  ((size_t)39204864)  // s bf16 A-frag, rows 512 x 512
#define O_XPSENT  ((size_t)39729152)  // xp_sent f32 [512][1536]
#define O_SOFRAG  ((size_t)42874880)  // sent_out bf16 A-frag, rows 512 x 512
#define O_SCORESS ((size_t)43399168)  // sent scores f32 [512]
#define WS_NEED   ((size_t)43401216)

// ---------------------------------------------------------------------------
// prep: all weight repacks.  Fragment-linear layout for B operands:
//   short index = ((nf*KF + kf)*64 + lane)*8 + j,
//   n = nf*16 + (lane&15),  k = kf*32 + (lane>>4)*8 + j,  value = B(k, n).
// ---------------------------------------------------------------------------
__global__ void k_prep(const float* wihf, const float* whhf,
                       const float* wihb, const float* whhb,
                       const float* sgihf, const float* sgihb,
                       const float* sghhf, const float* sghhb,
                       const float* wordW, const float* sentW,
                       const float* bihf, const float* bhhf,
                       const float* bihb, const float* bhhb,
                       const float* sgbihf, const float* sgbihb,
                       unsigned short* Wpwf, unsigned short* Wpwb,
                       unsigned short* Wpsgih,
                       unsigned short* WpshhF, unsigned short* WpshhB,
                       unsigned short* WpwW, unsigned short* WpsW,
                       float* biasWf, float* biasWb, float* bihCat)
{
    const int tid0 = blockIdx.x * blockDim.x + threadIdx.x;
    const int nth  = gridDim.x * blockDim.x;

    // A) word combined [r|z|xn|hn] x [e(256)|h(256)], both dirs. KF=16.
    for (int idx = tid0; idx < 2 * 524288; idx += nth) {
        int d = idx >> 19, sidx = idx & 524287;
        int j = sidx & 7, chunk = sidx >> 3;
        int lane = chunk & 63, nk = chunk >> 6;
        int kf = nk & 15, nf = nk >> 4;
        int n = nf * 16 + (lane & 15);
        int k = kf * 32 + (lane >> 4) * 8 + j;
        const float* Wih = d ? wihb : wihf;
        const float* Whh = d ? whhb : whhf;
        int g4 = n >> 8, jj = n & 255;
        float v = 0.f;
        if (k < 256) {
            if (g4 == 0) v = Wih[jj * 256 + k];
            else if (g4 == 1) v = Wih[(256 + jj) * 256 + k];
            else if (g4 == 2) v = Wih[(512 + jj) * 256 + k];
        } else {
            int kk = k - 256;
            if (g4 == 0) v = Whh[jj * 256 + kk];
            else if (g4 == 1) v = Whh[(256 + jj) * 256 + kk];
            else if (g4 == 3) v = Whh[(512 + jj) * 256 + kk];
        }
        (d ? Wpwb : Wpwf)[sidx] = f2bf(v);
    }
    // B) sentence Wih cat [1536n][512k]. KF=16.
    for (int idx = tid0; idx < 786432; idx += nth) {
        int j = idx & 7, chunk = idx >> 3;
        int lane = chunk & 63, nk = chunk >> 6;
        int kf = nk & 15, nf = nk >> 4;
        int n = nf * 16 + (lane & 15);
        int k = kf * 32 + (lane >> 4) * 8 + j;
        float v = (n < 768) ? sgihf[n * 512 + k] : sgihb[(n - 768) * 512 + k];
        Wpsgih[idx] = f2bf(v);
    }
    // C) sentence Whh f/b [768n][256k]. KF=8.
    for (int idx = tid0; idx < 2 * 196608; idx += nth) {
        int d = idx >= 196608;
        int sidx = d ? idx - 196608 : idx;
        int j = sidx & 7, chunk = sidx >> 3;
        int lane = chunk & 63, nk = chunk >> 6;
        int kf = nk & 7, nf = nk >> 3;
        int n = nf * 16 + (lane & 15);
        int k = kf * 32 + (lane >> 4) * 8 + j;
        float v = (d ? sghhb : sghhf)[n * 256 + k];
        (d ? WpshhB : WpshhF)[sidx] = f2bf(v);
    }
    // D) word_W / sent_W transposed: B(k,n) = W[k*512+n]. KF=16.
    for (int idx = tid0; idx < 2 * 262144; idx += nth) {
        int d = idx >> 18, sidx = idx & 262143;
        int j = sidx & 7, chunk = sidx >> 3;
        int lane = chunk & 63, nk = chunk >> 6;
        int kf = nk & 15, nf = nk >> 4;
        int n = nf * 16 + (lane & 15);
        int k = kf * 32 + (lane >> 4) * 8 + j;
        float v = (d ? sentW : wordW)[k * 512 + n];
        (d ? WpsW : WpwW)[sidx] = f2bf(v);
    }
    // E) word bias comb: [r: bih+bhh][z: bih+bhh][xn: bih][hn: bhh]
    for (int idx = tid0; idx < 2048; idx += nth) {
        int d = idx >> 10, i = idx & 1023;
        int g4 = i >> 8, j = i & 255;
        const float* bi = d ? bihb : bihf;
        const float* bh = d ? bhhb : bhhf;
        float v = (g4 == 0) ? bi[j] + bh[j]
                : (g4 == 1) ? bi[256 + j] + bh[256 + j]
                : (g4 == 2) ? bi[512 + j] : bh[512 + j];
        (d ? biasWb : biasWf)[i] = v;
    }
    // F) sentence bih cat
    for (int idx = tid0; idx < 1536; idx += nth)
        bihCat[idx] = (idx < 768) ? sgbihf[idx] : sgbihb[idx - 768];
}

// ---------------------------------------------------------------------------
// word bi-GRU: one WG per (sentence, dir). A=[e_t | h] in LDS (XOR-swizzled,
// double-buffered e), h fp32 in registers, fused 4-gate GEMM K=512.
// word_out written bf16 in A-fragment layout (rows r=(s*64+t)*32+b, 512 cols).
// ---------------------------------------------------------------------------
DEVINL void prefetchE(unsigned short (*Ab)[512], const int* xg, const float* embed,
                      int s, int t, int tid)
{
    const int brow = tid >> 3, c = tid & 7;
    const int tok = xg[(s * 32 + brow) * 64 + t];
    const f32x4* src = (const f32x4*)(embed + (size_t)tok * 256) + c * 8;
#pragma unroll
    for (int q = 0; q < 4; ++q) {
        f32x4 f0 = src[q * 2], f1 = src[q * 2 + 1];
        i32x4 pk;
        pk.x = (int)((unsigned)f2bf(f0.x) | ((unsigned)f2bf(f0.y) << 16));
        pk.y = (int)((unsigned)f2bf(f0.z) | ((unsigned)f2bf(f0.w) << 16));
        pk.z = (int)((unsigned)f2bf(f1.x) | ((unsigned)f2bf(f1.y) << 16));
        pk.w = (int)((unsigned)f2bf(f1.z) | ((unsigned)f2bf(f1.w) << 16));
        int kbyte = (c * 64 + q * 16) ^ ((brow & 7) << 4);
        *(i32x4*)((char*)&Ab[brow][0] + kbyte) = pk;
    }
}

__global__ __launch_bounds__(256, 1)
void k_gru_word(const int* xg, const float* embed, const float* stateW,
                const unsigned short* Wpwf_u, const unsigned short* Wpwb_u,
                const float* biasWf, const float* biasWb,
                unsigned short* wout)
{
    __shared__ unsigned short AbufS[2][32][512];   // 64 KiB static
    unsigned short (*Abuf)[32][512] = AbufS;

    const int tid = threadIdx.x, lane = tid & 63, w = tid >> 6;
    const int cid = blockIdx.x, s = cid >> 1, dir = cid & 1;
    const i32x4* Wp = (const i32x4*)(dir ? Wpwb_u : Wpwf_u);
    const float* bias = dir ? biasWb : biasWf;

    float hreg[4][2][4];
#pragma unroll
    for (int nfl = 0; nfl < 4; ++nfl) {
        int j = w * 64 + nfl * 16 + (lane & 15);
#pragma unroll
        for (int mf = 0; mf < 2; ++mf)
#pragma unroll
            for (int i = 0; i < 4; ++i) {
                int b = mf * 16 + (lane >> 4) * 4 + i;
                float h0 = stateW[dir * 8192 + b * 256 + j];
                hreg[nfl][mf][i] = h0;
                int byteoff = ((256 + j) * 2) ^ ((b & 7) << 4);
                *(unsigned short*)((char*)&Abuf[0][b][0] + byteoff) = f2bf(h0);
            }
    }
    const int tfirst = dir ? 63 : 0;
    prefetchE(Abuf[0], xg, embed, s, tfirst, tid);

    for (int ti = 0; ti < 64; ++ti) {
        __syncthreads();
        const int t = dir ? 63 - ti : ti;
        const int cur = ti & 1, nxt = cur ^ 1;
        if (ti < 63) prefetchE(Abuf[nxt], xg, embed, s, dir ? t - 1 : t + 1, tid);

        f32x4 acc[16][2];
#pragma unroll
        for (int nt = 0; nt < 16; ++nt) { acc[nt][0] = zero4(); acc[nt][1] = zero4(); }

#pragma unroll
        for (int kf = 0; kf < 16; ++kf) {
            const int row0 = lane & 15;
            const int boff = (kf * 64 + (lane >> 4) * 16) ^ ((row0 & 7) << 4);
            i32x4 a0 = *(const i32x4*)((const char*)&Abuf[cur][row0][0] + boff);
            i32x4 a1 = *(const i32x4*)((const char*)&Abuf[cur][16 + row0][0] + boff);
#pragma unroll
            for (int nt = 0; nt < 16; ++nt) {
                const int g4 = nt >> 2;
                if ((g4 == 2 && kf >= 8) || (g4 == 3 && kf < 8)) continue; // zero blocks
                const int nfg = g4 * 16 + w * 4 + (nt & 3);
                i32x4 bf = Wp[(nfg * 16 + kf) * 64 + lane];
                mfma16(acc[nt][0], a0, bf);
                mfma16(acc[nt][1], a1, bf);
            }
        }

#pragma unroll
        for (int nfl = 0; nfl < 4; ++nfl) {
            const int j = w * 64 + nfl * 16 + (lane & 15);
            const float br = bias[j], bz = bias[256 + j];
            const float bxn = bias[512 + j], bhn = bias[768 + j];
#pragma unroll
            for (int mf = 0; mf < 2; ++mf)
#pragma unroll
                for (int i = 0; i < 4; ++i) {
                    const int b = mf * 16 + (lane >> 4) * 4 + i;
                    float rv = sigm(acc[nfl][mf][i] + br);
                    float zv = sigm(acc[4 + nfl][mf][i] + bz);
                    float nv = tanh_(acc[8 + nfl][mf][i] + bxn +
                                     rv * (acc[12 + nfl][mf][i] + bhn));
                    float hnew = (1.f - zv) * nv + zv * hreg[nfl][mf][i];
                    hreg[nfl][mf][i] = hnew;
                    unsigned short hb = f2bf(hnew);
                    int byteoff = ((256 + j) * 2) ^ ((b & 7) << 4);
                    *(unsigned short*)((char*)&Abuf[nxt][b][0] + byteoff) = hb;
                    int r = (s * 64 + t) * 32 + b;
                    int hcol = dir * 256 + j;
                    wout[(((r >> 4) * 16 + (hcol >> 5)) * 64 + (r & 15) +
                          ((hcol >> 3) & 3) * 16) * 8 + (hcol & 7)] = hb;
                }
        }
    }
}

// ---------------------------------------------------------------------------
// attention scores: score[r] = sum_n tanh((A@W)[r,n] + b[n]) * proj[n]
// A in frag layout (K=512), W in frag layout. WG=16 row-blocks (4/wave).
// ---------------------------------------------------------------------------
__global__ void k_attn_score(const unsigned short* Afrag_u, const unsigned short* Wp_u,
                             const float* wb, const float* wp, float* scores)
{
    const int tid = threadIdx.x, lane = tid & 63, w = tid >> 6;
    const i32x4* A = (const i32x4*)Afrag_u;
    const i32x4* Wp = (const i32x4*)Wp_u;
    float partial[4][4] = {};
    int rblk[4];
#pragma unroll
    for (int mf = 0; mf < 4; ++mf) rblk[mf] = blockIdx.x * 16 + w * 4 + mf;

    for (int nf = 0; nf < 32; ++nf) {
        f32x4 acc[4];
#pragma unroll
        for (int mf = 0; mf < 4; ++mf) acc[mf] = zero4();
#pragma unroll
        for (int kf = 0; kf < 16; ++kf) {
            i32x4 bf = Wp[(nf * 16 + kf) * 64 + lane];
#pragma unroll
            for (int mf = 0; mf < 4; ++mf) {
                i32x4 a = A[(rblk[mf] * 16 + kf) * 64 + lane];
                mfma16(acc[mf], a, bf);
            }
        }
        const int n = nf * 16 + (lane & 15);
        const float wbn = wb[n], wpn = wp[n];
#pragma unroll
        for (int mf = 0; mf < 4; ++mf)
#pragma unroll
            for (int i = 0; i < 4; ++i)
                partial[mf][i] += tanh_(acc[mf][i] + wbn) * wpn;
    }
#pragma unroll
    for (int mf = 0; mf < 4; ++mf)
#pragma unroll
        for (int i = 0; i < 4; ++i) {
            float v = partial[mf][i];
            v += __shfl_xor(v, 1); v += __shfl_xor(v, 2);
            v += __shfl_xor(v, 4); v += __shfl_xor(v, 8);
            if ((lane & 15) == 0)
                scores[rblk[mf] * 16 + (lane >> 4) * 4 + i] = v;
        }
}

// softmax over T + weighted sum -> s (bf16 A-frag layout, rows r2=s*32+b)
__global__ void k_word_pool(const float* scores, const unsigned short* wout,
                            unsigned short* ssFrag)
{
    __shared__ float aL[64];
    const int l = threadIdx.x;                 // 64 threads
    const int bid = blockIdx.x;                // 0..511
    const int s = bid >> 5, b = bid & 31;
    float sc = scores[s * 2048 + l * 32 + b];
    float m = sc;
#pragma unroll
    for (int d = 1; d < 64; d <<= 1) m = fmaxf(m, __shfl_xor(m, d));
    float e = __expf(sc - m), sum = e;
#pragma unroll
    for (int d = 1; d < 64; d <<= 1) sum += __shfl_xor(sum, d);
    aL[l] = e * __builtin_amdgcn_rcpf(sum);
    __syncthreads();

    float acc[8] = {};
    const i32x4* WO = (const i32x4*)wout;
    for (int t = 0; t < 64; ++t) {
        float at = aL[t];
        int cidx = ((s * 128 + t * 2 + (b >> 4)) * 16 + (l >> 2)) * 64 +
                   (b & 15) + (l & 3) * 16;
        i32x4 ch = WO[cidx];
        acc[0] += at * bf2f((unsigned short)((unsigned)ch.x & 0xffffu));
        acc[1] += at * bf2f((unsigned short)((unsigned)ch.x >> 16));
        acc[2] += at * bf2f((unsigned short)((unsigned)ch.y & 0xffffu));
        acc[3] += at * bf2f((unsigned short)((unsigned)ch.y >> 16));
        acc[4] += at * bf2f((unsigned short)((unsigned)ch.z & 0xffffu));
        acc[5] += at * bf2f((unsigned short)((unsigned)ch.z >> 16));
        acc[6] += at * bf2f((unsigned short)((unsigned)ch.w & 0xffffu));
        acc[7] += at * bf2f((unsigned short)((unsigned)ch.w >> 16));
    }
    i32x4 pk;
    pk.x = (int)((unsigned)f2bf(acc[0]) | ((unsigned)f2bf(acc[1]) << 16));
    pk.y = (int)((unsigned)f2bf(acc[2]) | ((unsigned)f2bf(acc[3]) << 16));
    pk.z = (int)((unsigned)f2bf(acc[4]) | ((unsigned)f2bf(acc[5]) << 16));
    pk.w = (int)((unsigned)f2bf(acc[6]) | ((unsigned)f2bf(acc[7]) << 16));
    const int r2 = s * 32 + b;
    int cidx2 = ((r2 >> 4) * 16 + (l >> 2)) * 64 + (r2 & 15) + (l & 3) * 16;
    ((i32x4*)ssFrag)[cidx2] = pk;
}

// xp_sent[row][n] = (s @ sg_Wih_cat^T)[row][n] + bih_cat[n]
__global__ void k_sgih(const unsigned short* ssFrag_u, const unsigned short* Wp_u,
                       const float* bihCat, float* xpSent)
{
    const int tid = threadIdx.x, lane = tid & 63, w = tid >> 6;
    const int rblk = blockIdx.x, ncl = blockIdx.y;
    const i32x4* A = (const i32x4*)ssFrag_u;
    const i32x4* Wp = (const i32x4*)Wp_u;
    i32x4 a[16];
#pragma unroll
    for (int kf = 0; kf < 16; ++kf) a[kf] = A[(rblk * 16 + kf) * 64 + lane];
#pragma unroll
    for (int nfl = 0; nfl < 4; ++nfl) {
        const int nfg = ncl * 16 + w * 4 + nfl;
        f32x4 acc = zero4();
#pragma unroll
        for (int kf = 0; kf < 16; ++kf)
            mfma16(acc, a[kf], Wp[(nfg * 16 + kf) * 64 + lane]);
        const int n = nfg * 16 + (lane & 15);
        const float bb = bihCat[n];
#pragma unroll
        for (int i = 0; i < 4; ++i) {
            int row = rblk * 16 + (lane >> 4) * 4 + i;
            xpSent[row * 1536 + n] = acc[i] + bb;
        }
    }
}

// sentence bi-GRU: 2 WGs, 16 steps, K=256 recurrent GEMM, xp from global.
__global__ __launch_bounds__(256, 1)
void k_gru_sent(const float* stateS, const unsigned short* WpF_u,
                const unsigned short* WpB_u, const float* bhhf, const float* bhhb,
                const float* xpSent, unsigned short* soFrag)
{
    __shared__ unsigned short Abuf[2][32][256];   // 32 KiB
    const int tid = threadIdx.x, lane = tid & 63, w = tid >> 6;
    const int dir = blockIdx.x;
    const i32x4* Wp = (const i32x4*)(dir ? WpB_u : WpF_u);
    const float* bhh = dir ? bhhb : bhhf;

    float hreg[4][2][4];
#pragma unroll
    for (int nfl = 0; nfl < 4; ++nfl) {
        int j = w * 64 + nfl * 16 + (lane & 15);
#pragma unroll
        for (int mf = 0; mf < 2; ++mf)
#pragma unroll
            for (int i = 0; i < 4; ++i) {
                int b = mf * 16 + (lane >> 4) * 4 + i;
                float h0 = stateS[dir * 8192 + b * 256 + j];
                hreg[nfl][mf][i] = h0;
                int byteoff = (j * 2) ^ ((b & 7) << 4);
                *(unsigned short*)((char*)&Abuf[0][b][0] + byteoff) = f2bf(h0);
            }
    }
    for (int si = 0; si < 16; ++si) {
        __syncthreads();
        const int s = dir ? 15 - si : si;
        const int cur = si & 1, nxt = cur ^ 1;
        f32x4 acc[12][2];
#pragma unroll
        for (int nt = 0; nt < 12; ++nt) { acc[nt][0] = zero4(); acc[nt][1] = zero4(); }
#pragma unroll
        for (int kf = 0; kf < 8; ++kf) {
            const int row0 = lane & 15;
            const int boff = (kf * 64 + (lane >> 4) * 16) ^ ((row0 & 7) << 4);
            i32x4 a0 = *(const i32x4*)((const char*)&Abuf[cur][row0][0] + boff);
            i32x4 a1 = *(const i32x4*)((const char*)&Abuf[cur][16 + row0][0] + boff);
#pragma unroll
            for (int nt = 0; nt < 12; ++nt) {
                const int nfg = (nt >> 2) * 16 + w * 4 + (nt & 3);
                i32x4 bf = Wp[(nfg * 8 + kf) * 64 + lane];
                mfma16(acc[nt][0], a0, bf);
                mfma16(acc[nt][1], a1, bf);
            }
        }
#pragma unroll
        for (int nfl = 0; nfl < 4; ++nfl) {
            const int j = w * 64 + nfl * 16 + (lane & 15);
            const float bhr = bhh[j], bhz = bhh[256 + j], bhn = bhh[512 + j];
#pragma unroll
            for (int mf = 0; mf < 2; ++mf)
#pragma unroll
                for (int i = 0; i < 4; ++i) {
                    const int b = mf * 16 + (lane >> 4) * 4 + i;
                    const float* xp = xpSent + ((s * 32 + b) * 1536 + dir * 768);
                    float rv = sigm(xp[j] + acc[nfl][mf][i] + bhr);
                    float zv = sigm(xp[256 + j] + acc[4 + nfl][mf][i] + bhz);
                    float nv = tanh_(xp[512 + j] + rv * (acc[8 + nfl][mf][i] + bhn));
                    float hnew = (1.f - zv) * nv + zv * hreg[nfl][mf][i];
                    hreg[nfl][mf][i] = hnew;
                    unsigned short hb = f2bf(hnew);
                    int byteoff = (j * 2) ^ ((b & 7) << 4);
                    *(unsigned short*)((char*)&Abuf[nxt][b][0] + byteoff) = hb;
                    int r2 = s * 32 + b, hcol = dir * 256 + j;
                    soFrag[(((r2 >> 4) * 16 + (hcol >> 5)) * 64 + (r2 & 15) +
                            ((hcol >> 3) & 3) * 16) * 8 + (hcol & 7)] = hb;
                }
        }
    }
}

// sentence softmax over S + pool + final linear
__global__ void k_sent_pool_fin(const float* scoresS, const unsigned short* soFrag,
                                const float* finW, const float* finb, float* out)
{
    __shared__ float aL[16];
    __shared__ float pooled[512];
    const int l = threadIdx.x;   // 64
    const int b = blockIdx.x;    // 0..31
    float sc = (l < 16) ? scoresS[l * 32 + b] : -1e30f;
    float m = sc;
#pragma unroll
    for (int d = 1; d < 16; d <<= 1) m = fmaxf(m, __shfl_xor(m, d));
    float e = (l < 16) ? __expf(sc - m) : 0.f;
    float sum = e;
#pragma unroll
    for (int d = 1; d < 16; d <<= 1) sum += __shfl_xor(sum, d);
    if (l < 16) aL[l] = e * __builtin_amdgcn_rcpf(sum);
    __syncthreads();

    float acc[8] = {};
    const i32x4* SO = (const i32x4*)soFrag;
    for (int si = 0; si < 16; ++si) {
        float as = aL[si];
        int r2 = si * 32 + b;
        int cidx = ((r2 >> 4) * 16 + (l >> 2)) * 64 + (r2 & 15) + (l & 3) * 16;
        i32x4 ch = SO[cidx];
        acc[0] += as * bf2f((unsigned short)((unsigned)ch.x & 0xffffu));
        acc[1] += as * bf2f((unsigned short)((unsigned)ch.x >> 16));
        acc[2] += as * bf2f((unsigned short)((unsigned)ch.y & 0xffffu));
        acc[3] += as * bf2f((unsigned short)((unsigned)ch.y >> 16));
        acc[4] += as * bf2f((unsigned short)((unsigned)ch.z & 0xffffu));
        acc[5] += as * bf2f((unsigned short)((unsigned)ch.z >> 16));
        acc[6] += as * bf2f((unsigned short)((unsigned)ch.w & 0xffffu));
        acc[7] += as * bf2f((unsigned short)((unsigned)ch.w >> 16));
    }
#pragma unroll
    for (int q = 0; q < 8; ++q) pooled[l * 8 + q] = acc[q];
    __syncthreads();
    for (int c = l; c < 50; c += 64) {
        float v = finb[c];
        for (int k = 0; k < 512; ++k) v += pooled[k] * finW[c * 512 + k];
        out[b * 50 + c] = v;
    }
}

// ---------------------------------------------------------------------------
extern "C" void kernel_launch(void* const* d_in, const int* in_sizes, int n_in,
                              void* d_out, int out_size, void* d_ws, size_t ws_size,
                              hipStream_t stream)
{
    if (ws_size < WS_NEED) return;   // avoid OOB scribbling if ws too small

    const int*   x      = (const int*)d_in[0];
    const float* embed  = (const float*)d_in[1];
    const float* wgWihF = (const float*)d_in[2];
    const float* wgWhhF = (const float*)d_in[3];
    const float* wgBihF = (const float*)d_in[4];
    const float* wgBhhF = (const float*)d_in[5];
    const float* wgWihB = (const float*)d_in[6];
    const float* wgWhhB = (const float*)d_in[7];
    const float* wgBihB = (const float*)d_in[8];
    const float* wgBhhB = (const float*)d_in[9];
    const float* wordW  = (const float*)d_in[10];
    const float* wordB  = (const float*)d_in[11];
    const float* wordP  = (const float*)d_in[12];
    const float* sgWihF = (const float*)d_in[13];
    const float* sgWhhF = (const float*)d_in[14];
    const float* sgBihF = (const float*)d_in[15];
    const float* sgBhhF = (const float*)d_in[16];
    const float* sgWihB = (const float*)d_in[17];
    const float* sgWhhB = (const float*)d_in[18];
    const float* sgBihB = (const float*)d_in[19];
    const float* sgBhhB = (const float*)d_in[20];
    const float* sentWm = (const float*)d_in[21];
    const float* sentB  = (const float*)d_in[22];
    const float* sentP  = (const float*)d_in[23];
    const float* finW   = (const float*)d_in[24];
    const float* finB   = (const float*)d_in[25];
    const float* stateW = (const float*)d_in[26];
    const float* stateS = (const float*)d_in[27];

    char* ws = (char*)d_ws;
    unsigned short* Wpwf   = (unsigned short*)(ws + O_WPWF);
    unsigned short* Wpwb   = (unsigned short*)(ws + O_WPWB);
    unsigned short* Wpsgih = (unsigned short*)(ws + O_WPSGIH);
    unsigned short* WpshhF = (unsigned short*)(ws + O_WPSHHF);
    unsigned short* WpshhB = (unsigned short*)(ws + O_WPSHHB);
    unsigned short* WpwW   = (unsigned short*)(ws + O_WPWW);
    unsigned short* WpsW   = (unsigned short*)(ws + O_WPSW);
    float* biasWf  = (float*)(ws + O_BIASWF);
    float* biasWb  = (float*)(ws + O_BIASWB);
    float* bihCat  = (float*)(ws + O_BIHCAT);
    unsigned short* wout   = (unsigned short*)(ws + O_WOUT);
    float* scoresW = (float*)(ws + O_SCORESW);
    unsigned short* ssFrag = (unsigned short*)(ws + O_SSFRAG);
    float* xpSent  = (float*)(ws + O_XPSENT);
    unsigned short* soFrag = (unsigned short*)(ws + O_SOFRAG);
    float* scoresS = (float*)(ws + O_SCORESS);

    k_prep<<<512, 256, 0, stream>>>(wgWihF, wgWhhF, wgWihB, wgWhhB,
                                    sgWihF, sgWihB, sgWhhF, sgWhhB,
                                    wordW, sentWm,
                                    wgBihF, wgBhhF, wgBihB, wgBhhB,
                                    sgBihF, sgBihB,
                                    Wpwf, Wpwb, Wpsgih, WpshhF, WpshhB,
                                    WpwW, WpsW, biasWf, biasWb, bihCat);

    k_gru_word<<<32, 256, 0, stream>>>(x, embed, stateW, Wpwf, Wpwb,
                                       biasWf, biasWb, wout);

    k_attn_score<<<128, 256, 0, stream>>>(wout, WpwW, wordB, wordP, scoresW);
    k_word_pool<<<512, 64, 0, stream>>>(scoresW, wout, ssFrag);

    k_sgih<<<dim3(32, 6), 256, 0, stream>>>(ssFrag, Wpsgih, bihCat, xpSent);
    k_gru_sent<<<2, 256, 0, stream>>>(stateS, WpshhF, WpshhB, sgBhhF, sgBhhB,
                                      xpSent, soFrag);

    k_attn_score<<<2, 256, 0, stream>>>(soFrag, WpsW, sentB, sentP, scoresS);
    k_sent_pool_fin<<<32, 64, 0, stream>>>(scoresS, soFrag, finW, finB,
                                           (float*)d_out);
}

// Round 3
// 1579.794 us; speedup vs baseline: 1.9397x; 1.9397x over previous
//
#include <hip/hip_runtime.h>

// ---------------------------------------------------------------------------
// HAN forward on MI355X.
// S=16 sents, B=32 batch, T=64 tokens, E=H=256, 2H=512, NC=50, V=50000.
// R2: k_gru_word/k_gru_sent -> 512 threads (2 waves/SIMD) + 2-deep register
// ring prefetch of B-fragments (latency-bound on L2 at 1 wave/SIMD before:
// 32us/step vs ~5.5us L2-BW floor). Sent attn gets a 8-WG variant.
// ---------------------------------------------------------------------------

typedef float  f32x4  __attribute__((ext_vector_type(4)));
typedef int    i32x4  __attribute__((ext_vector_type(4)));
typedef __bf16 bf16x8 __attribute__((ext_vector_type(8)));

#define DEVINL static __device__ __forceinline__

DEVINL unsigned short f2bf(float f) {          // RNE float->bf16
    unsigned int x = __builtin_bit_cast(unsigned int, f);
    x = x + 0x7fffu + ((x >> 16) & 1u);
    return (unsigned short)(x >> 16);
}
DEVINL float bf2f(unsigned short u) {
    unsigned int x = ((unsigned int)u) << 16;
    return __builtin_bit_cast(float, x);
}
DEVINL float sigm(float x) { return __builtin_amdgcn_rcpf(1.f + __expf(-x)); }
DEVINL float tanh_(float x) {
    x = fminf(fmaxf(x, -20.f), 20.f);
    float e = __expf(-2.f * x);
    return (1.f - e) * __builtin_amdgcn_rcpf(1.f + e);
}
DEVINL void mfma16(f32x4& acc, i32x4 a, i32x4 b) {
    acc = __builtin_amdgcn_mfma_f32_16x16x32_bf16(
        __builtin_bit_cast(bf16x8, a), __builtin_bit_cast(bf16x8, b), acc, 0, 0, 0);
}
DEVINL f32x4 zero4() { f32x4 v = {0.f, 0.f, 0.f, 0.f}; return v; }

// ---- workspace layout (bytes, all 256-aligned) ----------------------------
#define O_WPWF    ((size_t)0)         // word comb fwd  [1024n][512k] bf16 frag
#define O_WPWB    ((size_t)1048576)
#define O_WPSGIH  ((size_t)2097152)   // sent Wih cat   [1536n][512k]
#define O_WPSHHF  ((size_t)3670016)   // sent Whh fwd   [768n][256k]
#define O_WPSHHB  ((size_t)4063232)
#define O_WPWW    ((size_t)4456448)   // word_W^T       [512n][512k]
#define O_WPSW    ((size_t)4980736)   // sent_W^T
#define O_BIASWF  ((size_t)5505024)   // word bias comb [4][256] f32
#define O_BIASWB  ((size_t)5509120)
#define O_BIHCAT  ((size_t)5513216)   // sent bih cat [1536] f32
#define O_WOUT    ((size_t)5519360)   // word_out bf16 A-frag, rows 32768 x 512
#define O_SCORESW ((size_t)39073792)  // word scores f32 [32768]
#define O_SSFRAG  ((size_t)39204864)  // s bf16 A-frag, rows 512 x 512
#define O_XPSENT  ((size_t)39729152)  // xp_sent f32 [512][1536]
#define O_SOFRAG  ((size_t)42874880)  // sent_out bf16 A-frag, rows 512 x 512
#define O_SCORESS ((size_t)43399168)  // sent scores f32 [512]
#define WS_NEED   ((size_t)43401216)

// ---------------------------------------------------------------------------
// prep: all weight repacks.  Fragment-linear layout for B operands:
//   short index = ((nf*KF + kf)*64 + lane)*8 + j,
//   n = nf*16 + (lane&15),  k = kf*32 + (lane>>4)*8 + j,  value = B(k, n).
// ---------------------------------------------------------------------------
__global__ void k_prep(const float* wihf, const float* whhf,
                       const float* wihb, const float* whhb,
                       const float* sgihf, const float* sgihb,
                       const float* sghhf, const float* sghhb,
                       const float* wordW, const float* sentW,
                       const float* bihf, const float* bhhf,
                       const float* bihb, const float* bhhb,
                       const float* sgbihf, const float* sgbihb,
                       unsigned short* Wpwf, unsigned short* Wpwb,
                       unsigned short* Wpsgih,
                       unsigned short* WpshhF, unsigned short* WpshhB,
                       unsigned short* WpwW, unsigned short* WpsW,
                       float* biasWf, float* biasWb, float* bihCat)
{
    const int tid0 = blockIdx.x * blockDim.x + threadIdx.x;
    const int nth  = gridDim.x * blockDim.x;

    // A) word combined [r|z|xn|hn] x [e(256)|h(256)], both dirs. KF=16.
    for (int idx = tid0; idx < 2 * 524288; idx += nth) {
        int d = idx >> 19, sidx = idx & 524287;
        int j = sidx & 7, chunk = sidx >> 3;
        int lane = chunk & 63, nk = chunk >> 6;
        int kf = nk & 15, nf = nk >> 4;
        int n = nf * 16 + (lane & 15);
        int k = kf * 32 + (lane >> 4) * 8 + j;
        const float* Wih = d ? wihb : wihf;
        const float* Whh = d ? whhb : whhf;
        int g4 = n >> 8, jj = n & 255;
        float v = 0.f;
        if (k < 256) {
            if (g4 == 0) v = Wih[jj * 256 + k];
            else if (g4 == 1) v = Wih[(256 + jj) * 256 + k];
            else if (g4 == 2) v = Wih[(512 + jj) * 256 + k];
        } else {
            int kk = k - 256;
            if (g4 == 0) v = Whh[jj * 256 + kk];
            else if (g4 == 1) v = Whh[(256 + jj) * 256 + kk];
            else if (g4 == 3) v = Whh[(512 + jj) * 256 + kk];
        }
        (d ? Wpwb : Wpwf)[sidx] = f2bf(v);
    }
    // B) sentence Wih cat [1536n][512k]. KF=16.
    for (int idx = tid0; idx < 786432; idx += nth) {
        int j = idx & 7, chunk = idx >> 3;
        int lane = chunk & 63, nk = chunk >> 6;
        int kf = nk & 15, nf = nk >> 4;
        int n = nf * 16 + (lane & 15);
        int k = kf * 32 + (lane >> 4) * 8 + j;
        float v = (n < 768) ? sgihf[n * 512 + k] : sgihb[(n - 768) * 512 + k];
        Wpsgih[idx] = f2bf(v);
    }
    // C) sentence Whh f/b [768n][256k]. KF=8.
    for (int idx = tid0; idx < 2 * 196608; idx += nth) {
        int d = idx >= 196608;
        int sidx = d ? idx - 196608 : idx;
        int j = sidx & 7, chunk = sidx >> 3;
        int lane = chunk & 63, nk = chunk >> 6;
        int kf = nk & 7, nf = nk >> 3;
        int n = nf * 16 + (lane & 15);
        int k = kf * 32 + (lane >> 4) * 8 + j;
        float v = (d ? sghhb : sghhf)[n * 256 + k];
        (d ? WpshhB : WpshhF)[sidx] = f2bf(v);
    }
    // D) word_W / sent_W transposed: B(k,n) = W[k*512+n]. KF=16.
    for (int idx = tid0; idx < 2 * 262144; idx += nth) {
        int d = idx >> 18, sidx = idx & 262143;
        int j = sidx & 7, chunk = sidx >> 3;
        int lane = chunk & 63, nk = chunk >> 6;
        int kf = nk & 15, nf = nk >> 4;
        int n = nf * 16 + (lane & 15);
        int k = kf * 32 + (lane >> 4) * 8 + j;
        float v = (d ? sentW : wordW)[k * 512 + n];
        (d ? WpsW : WpwW)[sidx] = f2bf(v);
    }
    // E) word bias comb: [r: bih+bhh][z: bih+bhh][xn: bih][hn: bhh]
    for (int idx = tid0; idx < 2048; idx += nth) {
        int d = idx >> 10, i = idx & 1023;
        int g4 = i >> 8, j = i & 255;
        const float* bi = d ? bihb : bihf;
        const float* bh = d ? bhhb : bhhf;
        float v = (g4 == 0) ? bi[j] + bh[j]
                : (g4 == 1) ? bi[256 + j] + bh[256 + j]
                : (g4 == 2) ? bi[512 + j] : bh[512 + j];
        (d ? biasWb : biasWf)[i] = v;
    }
    // F) sentence bih cat
    for (int idx = tid0; idx < 1536; idx += nth)
        bihCat[idx] = (idx < 768) ? sgbihf[idx] : sgbihb[idx - 768];
}

// ---------------------------------------------------------------------------
// word bi-GRU: one WG (512 thr, 8 waves) per (sentence, dir).
// A=[e_t | h] in LDS (XOR-swizzled, double-buffered), h fp32 in registers,
// fused 4-gate GEMM K=512. B-frags: 2-deep register ring prefetch.
// ---------------------------------------------------------------------------
DEVINL void prefetchE(unsigned short (*Ab)[512], const int* xg, const float* embed,
                      int s, int t, int tid)
{
    const int brow = tid >> 4, c = tid & 15;          // 32 rows x 16 thr
    const int tok = xg[(s * 32 + brow) * 64 + t];
    const f32x4* src = (const f32x4*)(embed + (size_t)tok * 256) + c * 4;
#pragma unroll
    for (int q = 0; q < 2; ++q) {
        f32x4 f0 = src[q * 2], f1 = src[q * 2 + 1];
        i32x4 pk;
        pk.x = (int)((unsigned)f2bf(f0.x) | ((unsigned)f2bf(f0.y) << 16));
        pk.y = (int)((unsigned)f2bf(f0.z) | ((unsigned)f2bf(f0.w) << 16));
        pk.z = (int)((unsigned)f2bf(f1.x) | ((unsigned)f2bf(f1.y) << 16));
        pk.w = (int)((unsigned)f2bf(f1.z) | ((unsigned)f2bf(f1.w) << 16));
        int kbyte = (c * 32 + q * 16) ^ ((brow & 7) << 4);
        *(i32x4*)((char*)&Ab[brow][0] + kbyte) = pk;
    }
}

__global__ __launch_bounds__(512, 2)
void k_gru_word(const int* xg, const float* embed, const float* stateW,
                const unsigned short* Wpwf_u, const unsigned short* Wpwb_u,
                const float* biasWf, const float* biasWb,
                unsigned short* wout)
{
    __shared__ unsigned short Abuf[2][32][512];   // 64 KiB

    const int tid = threadIdx.x, lane = tid & 63, w = tid >> 6;   // w 0..7
    const int cid = blockIdx.x, s = cid >> 1, dir = cid & 1;
    const i32x4* Wp = (const i32x4*)(dir ? Wpwb_u : Wpwf_u);
    const float* bias = dir ? biasWb : biasWf;

    float hreg[2][2][4];
#pragma unroll
    for (int q = 0; q < 2; ++q) {
        int j = w * 32 + q * 16 + (lane & 15);
#pragma unroll
        for (int mf = 0; mf < 2; ++mf)
#pragma unroll
            for (int i = 0; i < 4; ++i) {
                int b = mf * 16 + (lane >> 4) * 4 + i;
                float h0 = stateW[dir * 8192 + b * 256 + j];
                hreg[q][mf][i] = h0;
                int byteoff = ((256 + j) * 2) ^ ((b & 7) << 4);
                *(unsigned short*)((char*)&Abuf[0][b][0] + byteoff) = f2bf(h0);
            }
    }
    const int tfirst = dir ? 63 : 0;
    prefetchE(Abuf[0], xg, embed, s, tfirst, tid);

    // B-frag slot loader: slots {0,1}=r, {2,3}=z, {4,5}=xn(kf<8)/hn(kf>=8)
    const int nq = w * 2;

    for (int ti = 0; ti < 64; ++ti) {
        __syncthreads();
        const int t = dir ? 63 - ti : ti;
        const int cur = ti & 1, nxt = cur ^ 1;
        if (ti < 63) prefetchE(Abuf[nxt], xg, embed, s, dir ? t - 1 : t + 1, tid);

        f32x4 acc[8][2];
#pragma unroll
        for (int nt = 0; nt < 8; ++nt) { acc[nt][0] = zero4(); acc[nt][1] = zero4(); }

        i32x4 bbuf[3][6];
#define LOADB_W(KF, DST)                                                     \
        {                                                                    \
            const int gX = ((KF) < 8) ? 32 : 48;                             \
            DST[0] = Wp[((0 + nq + 0) * 16 + (KF)) * 64 + lane];             \
            DST[1] = Wp[((0 + nq + 1) * 16 + (KF)) * 64 + lane];             \
            DST[2] = Wp[((16 + nq + 0) * 16 + (KF)) * 64 + lane];            \
            DST[3] = Wp[((16 + nq + 1) * 16 + (KF)) * 64 + lane];            \
            DST[4] = Wp[((gX + nq + 0) * 16 + (KF)) * 64 + lane];            \
            DST[5] = Wp[((gX + nq + 1) * 16 + (KF)) * 64 + lane];            \
        }
        LOADB_W(0, bbuf[0]);
        LOADB_W(1, bbuf[1]);

#pragma unroll
        for (int kf = 0; kf < 16; ++kf) {
            if (kf < 14) LOADB_W(kf + 2, bbuf[(kf + 2) % 3]);
            const int row0 = lane & 15;
            const int boff = (kf * 64 + (lane >> 4) * 16) ^ ((row0 & 7) << 4);
            i32x4 a0 = *(const i32x4*)((const char*)&Abuf[cur][row0][0] + boff);
            i32x4 a1 = *(const i32x4*)((const char*)&Abuf[cur][16 + row0][0] + boff);
            const i32x4* bc = bbuf[kf % 3];
#pragma unroll
            for (int q = 0; q < 2; ++q) {
                mfma16(acc[0 + q][0], a0, bc[q]);     mfma16(acc[0 + q][1], a1, bc[q]);
                mfma16(acc[2 + q][0], a0, bc[2 + q]); mfma16(acc[2 + q][1], a1, bc[2 + q]);
                if (kf < 8) { mfma16(acc[4 + q][0], a0, bc[4 + q]);
                              mfma16(acc[4 + q][1], a1, bc[4 + q]); }
                else        { mfma16(acc[6 + q][0], a0, bc[4 + q]);
                              mfma16(acc[6 + q][1], a1, bc[4 + q]); }
            }
        }
#undef LOADB_W

#pragma unroll
        for (int q = 0; q < 2; ++q) {
            const int j = w * 32 + q * 16 + (lane & 15);
            const float br = bias[j], bz = bias[256 + j];
            const float bxn = bias[512 + j], bhn = bias[768 + j];
#pragma unroll
            for (int mf = 0; mf < 2; ++mf)
#pragma unroll
                for (int i = 0; i < 4; ++i) {
                    const int b = mf * 16 + (lane >> 4) * 4 + i;
                    float rv = sigm(acc[q][mf][i] + br);
                    float zv = sigm(acc[2 + q][mf][i] + bz);
                    float nv = tanh_(acc[4 + q][mf][i] + bxn +
                                     rv * (acc[6 + q][mf][i] + bhn));
                    float hnew = (1.f - zv) * nv + zv * hreg[q][mf][i];
                    hreg[q][mf][i] = hnew;
                    unsigned short hb = f2bf(hnew);
                    int byteoff = ((256 + j) * 2) ^ ((b & 7) << 4);
                    *(unsigned short*)((char*)&Abuf[nxt][b][0] + byteoff) = hb;
                    int r = (s * 64 + t) * 32 + b;
                    int hcol = dir * 256 + j;
                    wout[(((r >> 4) * 16 + (hcol >> 5)) * 64 + (r & 15) +
                          ((hcol >> 3) & 3) * 16) * 8 + (hcol & 7)] = hb;
                }
        }
    }
}

// ---------------------------------------------------------------------------
// attention scores: score[r] = sum_n tanh((A@W)[r,n] + b[n]) * proj[n]
// A in frag layout (K=512), W in frag layout. WG=16 row-blocks (4/wave).
// ---------------------------------------------------------------------------
__global__ void k_attn_score(const unsigned short* Afrag_u, const unsigned short* Wp_u,
                             const float* wb, const float* wp, float* scores)
{
    const int tid = threadIdx.x, lane = tid & 63, w = tid >> 6;
    const i32x4* A = (const i32x4*)Afrag_u;
    const i32x4* Wp = (const i32x4*)Wp_u;
    float partial[4][4] = {};
    int rblk[4];
#pragma unroll
    for (int mf = 0; mf < 4; ++mf) rblk[mf] = blockIdx.x * 16 + w * 4 + mf;

    for (int nf = 0; nf < 32; ++nf) {
        f32x4 acc[4];
#pragma unroll
        for (int mf = 0; mf < 4; ++mf) acc[mf] = zero4();
#pragma unroll
        for (int kf = 0; kf < 16; ++kf) {
            i32x4 bf = Wp[(nf * 16 + kf) * 64 + lane];
#pragma unroll
            for (int mf = 0; mf < 4; ++mf) {
                i32x4 a = A[(rblk[mf] * 16 + kf) * 64 + lane];
                mfma16(acc[mf], a, bf);
            }
        }
        const int n = nf * 16 + (lane & 15);
        const float wbn = wb[n], wpn = wp[n];
#pragma unroll
        for (int mf = 0; mf < 4; ++mf)
#pragma unroll
            for (int i = 0; i < 4; ++i)
                partial[mf][i] += tanh_(acc[mf][i] + wbn) * wpn;
    }
#pragma unroll
    for (int mf = 0; mf < 4; ++mf)
#pragma unroll
        for (int i = 0; i < 4; ++i) {
            float v = partial[mf][i];
            v += __shfl_xor(v, 1); v += __shfl_xor(v, 2);
            v += __shfl_xor(v, 4); v += __shfl_xor(v, 8);
            if ((lane & 15) == 0)
                scores[rblk[mf] * 16 + (lane >> 4) * 4 + i] = v;
        }
}

// small-row variant: 1 row-block per wave, 4 per WG (for 512-row inputs)
__global__ void k_attn_score_small(const unsigned short* Afrag_u,
                                   const unsigned short* Wp_u,
                                   const float* wb, const float* wp, float* scores)
{
    const int tid = threadIdx.x, lane = tid & 63, w = tid >> 6;
    const int rblk = blockIdx.x * 4 + w;
    const i32x4* A = (const i32x4*)Afrag_u;
    const i32x4* Wp = (const i32x4*)Wp_u;
    float partial[4] = {};

    for (int nf = 0; nf < 32; ++nf) {
        f32x4 acc = zero4();
#pragma unroll
        for (int kf = 0; kf < 16; ++kf) {
            i32x4 bf = Wp[(nf * 16 + kf) * 64 + lane];
            i32x4 a  = A[(rblk * 16 + kf) * 64 + lane];
            mfma16(acc, a, bf);
        }
        const int n = nf * 16 + (lane & 15);
        const float wbn = wb[n], wpn = wp[n];
#pragma unroll
        for (int i = 0; i < 4; ++i)
            partial[i] += tanh_(acc[i] + wbn) * wpn;
    }
#pragma unroll
    for (int i = 0; i < 4; ++i) {
        float v = partial[i];
        v += __shfl_xor(v, 1); v += __shfl_xor(v, 2);
        v += __shfl_xor(v, 4); v += __shfl_xor(v, 8);
        if ((lane & 15) == 0)
            scores[rblk * 16 + (lane >> 4) * 4 + i] = v;
    }
}

// softmax over T + weighted sum -> s (bf16 A-frag layout, rows r2=s*32+b)
__global__ void k_word_pool(const float* scores, const unsigned short* wout,
                            unsigned short* ssFrag)
{
    __shared__ float aL[64];
    const int l = threadIdx.x;                 // 64 threads
    const int bid = blockIdx.x;                // 0..511
    const int s = bid >> 5, b = bid & 31;
    float sc = scores[s * 2048 + l * 32 + b];
    float m = sc;
#pragma unroll
    for (int d = 1; d < 64; d <<= 1) m = fmaxf(m, __shfl_xor(m, d));
    float e = __expf(sc - m), sum = e;
#pragma unroll
    for (int d = 1; d < 64; d <<= 1) sum += __shfl_xor(sum, d);
    aL[l] = e * __builtin_amdgcn_rcpf(sum);
    __syncthreads();

    float acc[8] = {};
    const i32x4* WO = (const i32x4*)wout;
    for (int t = 0; t < 64; ++t) {
        float at = aL[t];
        int cidx = ((s * 128 + t * 2 + (b >> 4)) * 16 + (l >> 2)) * 64 +
                   (b & 15) + (l & 3) * 16;
        i32x4 ch = WO[cidx];
        acc[0] += at * bf2f((unsigned short)((unsigned)ch.x & 0xffffu));
        acc[1] += at * bf2f((unsigned short)((unsigned)ch.x >> 16));
        acc[2] += at * bf2f((unsigned short)((unsigned)ch.y & 0xffffu));
        acc[3] += at * bf2f((unsigned short)((unsigned)ch.y >> 16));
        acc[4] += at * bf2f((unsigned short)((unsigned)ch.z & 0xffffu));
        acc[5] += at * bf2f((unsigned short)((unsigned)ch.z >> 16));
        acc[6] += at * bf2f((unsigned short)((unsigned)ch.w & 0xffffu));
        acc[7] += at * bf2f((unsigned short)((unsigned)ch.w >> 16));
    }
    i32x4 pk;
    pk.x = (int)((unsigned)f2bf(acc[0]) | ((unsigned)f2bf(acc[1]) << 16));
    pk.y = (int)((unsigned)f2bf(acc[2]) | ((unsigned)f2bf(acc[3]) << 16));
    pk.z = (int)((unsigned)f2bf(acc[4]) | ((unsigned)f2bf(acc[5]) << 16));
    pk.w = (int)((unsigned)f2bf(acc[6]) | ((unsigned)f2bf(acc[7]) << 16));
    const int r2 = s * 32 + b;
    int cidx2 = ((r2 >> 4) * 16 + (l >> 2)) * 64 + (r2 & 15) + (l & 3) * 16;
    ((i32x4*)ssFrag)[cidx2] = pk;
}

// xp_sent[row][n] = (s @ sg_Wih_cat^T)[row][n] + bih_cat[n]
__global__ void k_sgih(const unsigned short* ssFrag_u, const unsigned short* Wp_u,
                       const float* bihCat, float* xpSent)
{
    const int tid = threadIdx.x, lane = tid & 63, w = tid >> 6;
    const int rblk = blockIdx.x, ncl = blockIdx.y;
    const i32x4* A = (const i32x4*)ssFrag_u;
    const i32x4* Wp = (const i32x4*)Wp_u;
    i32x4 a[16];
#pragma unroll
    for (int kf = 0; kf < 16; ++kf) a[kf] = A[(rblk * 16 + kf) * 64 + lane];
#pragma unroll
    for (int nfl = 0; nfl < 4; ++nfl) {
        const int nfg = ncl * 16 + w * 4 + nfl;
        f32x4 acc = zero4();
#pragma unroll
        for (int kf = 0; kf < 16; ++kf)
            mfma16(acc, a[kf], Wp[(nfg * 16 + kf) * 64 + lane]);
        const int n = nfg * 16 + (lane & 15);
        const float bb = bihCat[n];
#pragma unroll
        for (int i = 0; i < 4; ++i) {
            int row = rblk * 16 + (lane >> 4) * 4 + i;
            xpSent[row * 1536 + n] = acc[i] + bb;
        }
    }
}

// sentence bi-GRU: 2 WGs (512 thr), 16 steps, K=256 recurrent GEMM.
__global__ __launch_bounds__(512, 2)
void k_gru_sent(const float* stateS, const unsigned short* WpF_u,
                const unsigned short* WpB_u, const float* bhhf, const float* bhhb,
                const float* xpSent, unsigned short* soFrag)
{
    __shared__ unsigned short Abuf[2][32][256];   // 32 KiB
    const int tid = threadIdx.x, lane = tid & 63, w = tid >> 6;  // w 0..7
    const int dir = blockIdx.x;
    const i32x4* Wp = (const i32x4*)(dir ? WpB_u : WpF_u);
    const float* bhh = dir ? bhhb : bhhf;
    const int nq = w * 2;

    float hreg[2][2][4];
#pragma unroll
    for (int q = 0; q < 2; ++q) {
        int j = w * 32 + q * 16 + (lane & 15);
#pragma unroll
        for (int mf = 0; mf < 2; ++mf)
#pragma unroll
            for (int i = 0; i < 4; ++i) {
                int b = mf * 16 + (lane >> 4) * 4 + i;
                float h0 = stateS[dir * 8192 + b * 256 + j];
                hreg[q][mf][i] = h0;
                int byteoff = (j * 2) ^ ((b & 7) << 4);
                *(unsigned short*)((char*)&Abuf[0][b][0] + byteoff) = f2bf(h0);
            }
    }
    for (int si = 0; si < 16; ++si) {
        __syncthreads();
        const int s = dir ? 15 - si : si;
        const int cur = si & 1, nxt = cur ^ 1;
        f32x4 acc[6][2];
#pragma unroll
        for (int nt = 0; nt < 6; ++nt) { acc[nt][0] = zero4(); acc[nt][1] = zero4(); }

        i32x4 bbuf[3][6];
#define LOADB_S(KF, DST)                                                     \
        {                                                                    \
            DST[0] = Wp[((0 + nq + 0) * 8 + (KF)) * 64 + lane];              \
            DST[1] = Wp[((0 + nq + 1) * 8 + (KF)) * 64 + lane];              \
            DST[2] = Wp[((16 + nq + 0) * 8 + (KF)) * 64 + lane];             \
            DST[3] = Wp[((16 + nq + 1) * 8 + (KF)) * 64 + lane];             \
            DST[4] = Wp[((32 + nq + 0) * 8 + (KF)) * 64 + lane];             \
            DST[5] = Wp[((32 + nq + 1) * 8 + (KF)) * 64 + lane];             \
        }
        LOADB_S(0, bbuf[0]);
        LOADB_S(1, bbuf[1]);
#pragma unroll
        for (int kf = 0; kf < 8; ++kf) {
            if (kf < 6) LOADB_S(kf + 2, bbuf[(kf + 2) % 3]);
            const int row0 = lane & 15;
            const int boff = (kf * 64 + (lane >> 4) * 16) ^ ((row0 & 7) << 4);
            i32x4 a0 = *(const i32x4*)((const char*)&Abuf[cur][row0][0] + boff);
            i32x4 a1 = *(const i32x4*)((const char*)&Abuf[cur][16 + row0][0] + boff);
            const i32x4* bc = bbuf[kf % 3];
#pragma unroll
            for (int q = 0; q < 2; ++q) {
                mfma16(acc[0 + q][0], a0, bc[q]);     mfma16(acc[0 + q][1], a1, bc[q]);
                mfma16(acc[2 + q][0], a0, bc[2 + q]); mfma16(acc[2 + q][1], a1, bc[2 + q]);
                mfma16(acc[4 + q][0], a0, bc[4 + q]); mfma16(acc[4 + q][1], a1, bc[4 + q]);
            }
        }
#undef LOADB_S

#pragma unroll
        for (int q = 0; q < 2; ++q) {
            const int j = w * 32 + q * 16 + (lane & 15);
            const float bhr = bhh[j], bhz = bhh[256 + j], bhn = bhh[512 + j];
#pragma unroll
            for (int mf = 0; mf < 2; ++mf)
#pragma unroll
                for (int i = 0; i < 4; ++i) {
                    const int b = mf * 16 + (lane >> 4) * 4 + i;
                    const float* xp = xpSent + ((s * 32 + b) * 1536 + dir * 768);
                    float rv = sigm(xp[j] + acc[q][mf][i] + bhr);
                    float zv = sigm(xp[256 + j] + acc[2 + q][mf][i] + bhz);
                    float nv = tanh_(xp[512 + j] + rv * (acc[4 + q][mf][i] + bhn));
                    float hnew = (1.f - zv) * nv + zv * hreg[q][mf][i];
                    hreg[q][mf][i] = hnew;
                    unsigned short hb = f2bf(hnew);
                    int byteoff = (j * 2) ^ ((b & 7) << 4);
                    *(unsigned short*)((char*)&Abuf[nxt][b][0] + byteoff) = hb;
                    int r2 = s * 32 + b, hcol = dir * 256 + j;
                    soFrag[(((r2 >> 4) * 16 + (hcol >> 5)) * 64 + (r2 & 15) +
                            ((hcol >> 3) & 3) * 16) * 8 + (hcol & 7)] = hb;
                }
        }
    }
}

// sentence softmax over S + pool + final linear
__global__ void k_sent_pool_fin(const float* scoresS, const unsigned short* soFrag,
                                const float* finW, const float* finb, float* out)
{
    __shared__ float aL[16];
    __shared__ float pooled[512];
    const int l = threadIdx.x;   // 64
    const int b = blockIdx.x;    // 0..31
    float sc = (l < 16) ? scoresS[l * 32 + b] : -1e30f;
    float m = sc;
#pragma unroll
    for (int d = 1; d < 16; d <<= 1) m = fmaxf(m, __shfl_xor(m, d));
    float e = (l < 16) ? __expf(sc - m) : 0.f;
    float sum = e;
#pragma unroll
    for (int d = 1; d < 16; d <<= 1) sum += __shfl_xor(sum, d);
    if (l < 16) aL[l] = e * __builtin_amdgcn_rcpf(sum);
    __syncthreads();

    float acc[8] = {};
    const i32x4* SO = (const i32x4*)soFrag;
    for (int si = 0; si < 16; ++si) {
        float as = aL[si];
        int r2 = si * 32 + b;
        int cidx = ((r2 >> 4) * 16 + (l >> 2)) * 64 + (r2 & 15) + (l & 3) * 16;
        i32x4 ch = SO[cidx];
        acc[0] += as * bf2f((unsigned short)((unsigned)ch.x & 0xffffu));
        acc[1] += as * bf2f((unsigned short)((unsigned)ch.x >> 16));
        acc[2] += as * bf2f((unsigned short)((unsigned)ch.y & 0xffffu));
        acc[3] += as * bf2f((unsigned short)((unsigned)ch.y >> 16));
        acc[4] += as * bf2f((unsigned short)((unsigned)ch.z & 0xffffu));
        acc[5] += as * bf2f((unsigned short)((unsigned)ch.z >> 16));
        acc[6] += as * bf2f((unsigned short)((unsigned)ch.w & 0xffffu));
        acc[7] += as * bf2f((unsigned short)((unsigned)ch.w >> 16));
    }
#pragma unroll
    for (int q = 0; q < 8; ++q) pooled[l * 8 + q] = acc[q];
    __syncthreads();
    for (int c = l; c < 50; c += 64) {
        float v = finb[c];
        for (int k = 0; k < 512; ++k) v += pooled[k] * finW[c * 512 + k];
        out[b * 50 + c] = v;
    }
}

// ---------------------------------------------------------------------------
extern "C" void kernel_launch(void* const* d_in, const int* in_sizes, int n_in,
                              void* d_out, int out_size, void* d_ws, size_t ws_size,
                              hipStream_t stream)
{
    if (ws_size < WS_NEED) return;   // avoid OOB scribbling if ws too small

    const int*   x      = (const int*)d_in[0];
    const float* embed  = (const float*)d_in[1];
    const float* wgWihF = (const float*)d_in[2];
    const float* wgWhhF = (const float*)d_in[3];
    const float* wgBihF = (const float*)d_in[4];
    const float* wgBhhF = (const float*)d_in[5];
    const float* wgWihB = (const float*)d_in[6];
    const float* wgWhhB = (const float*)d_in[7];
    const float* wgBihB = (const float*)d_in[8];
    const float* wgBhhB = (const float*)d_in[9];
    const float* wordW  = (const float*)d_in[10];
    const float* wordB  = (const float*)d_in[11];
    const float* wordP  = (const float*)d_in[12];
    const float* sgWihF = (const float*)d_in[13];
    const float* sgWhhF = (const float*)d_in[14];
    const float* sgBihF = (const float*)d_in[15];
    const float* sgBhhF = (const float*)d_in[16];
    const float* sgWihB = (const float*)d_in[17];
    const float* sgWhhB = (const float*)d_in[18];
    const float* sgBihB = (const float*)d_in[19];
    const float* sgBhhB = (const float*)d_in[20];
    const float* sentWm = (const float*)d_in[21];
    const float* sentB  = (const float*)d_in[22];
    const float* sentP  = (const float*)d_in[23];
    const float* finW   = (const float*)d_in[24];
    const float* finB   = (const float*)d_in[25];
    const float* stateW = (const float*)d_in[26];
    const float* stateS = (const float*)d_in[27];

    char* ws = (char*)d_ws;
    unsigned short* Wpwf   = (unsigned short*)(ws + O_WPWF);
    unsigned short* Wpwb   = (unsigned short*)(ws + O_WPWB);
    unsigned short* Wpsgih = (unsigned short*)(ws + O_WPSGIH);
    unsigned short* WpshhF = (unsigned short*)(ws + O_WPSHHF);
    unsigned short* WpshhB = (unsigned short*)(ws + O_WPSHHB);
    unsigned short* WpwW   = (unsigned short*)(ws + O_WPWW);
    unsigned short* WpsW   = (unsigned short*)(ws + O_WPSW);
    float* biasWf  = (float*)(ws + O_BIASWF);
    float* biasWb  = (float*)(ws + O_BIASWB);
    float* bihCat  = (float*)(ws + O_BIHCAT);
    unsigned short* wout   = (unsigned short*)(ws + O_WOUT);
    float* scoresW = (float*)(ws + O_SCORESW);
    unsigned short* ssFrag = (unsigned short*)(ws + O_SSFRAG);
    float* xpSent  = (float*)(ws + O_XPSENT);
    unsigned short* soFrag = (unsigned short*)(ws + O_SOFRAG);
    float* scoresS = (float*)(ws + O_SCORESS);

    k_prep<<<512, 256, 0, stream>>>(wgWihF, wgWhhF, wgWihB, wgWhhB,
                                    sgWihF, sgWihB, sgWhhF, sgWhhB,
                                    wordW, sentWm,
                                    wgBihF, wgBhhF, wgBihB, wgBhhB,
                                    sgBihF, sgBihB,
                                    Wpwf, Wpwb, Wpsgih, WpshhF, WpshhB,
                                    WpwW, WpsW, biasWf, biasWb, bihCat);

    k_gru_word<<<32, 512, 0, stream>>>(x, embed, stateW, Wpwf, Wpwb,
                                       biasWf, biasWb, wout);

    k_attn_score<<<128, 256, 0, stream>>>(wout, WpwW, wordB, wordP, scoresW);
    k_word_pool<<<512, 64, 0, stream>>>(scoresW, wout, ssFrag);

    k_sgih<<<dim3(32, 6), 256, 0, stream>>>(ssFrag, Wpsgih, bihCat, xpSent);
    k_gru_sent<<<2, 512, 0, stream>>>(stateS, WpshhF, WpshhB, sgBhhF, sgBhhB,
                                      xpSent, soFrag);

    k_attn_score_small<<<8, 256, 0, stream>>>(soFrag, WpsW, sentB, sentP, scoresS);
    k_sent_pool_fin<<<32, 64, 0, stream>>>(scoresS, soFrag, finW, finB,
                                           (float*)d_out);
}

// Round 4
// 1213.939 us; speedup vs baseline: 2.5242x; 1.3014x over previous
//
#include <hip/hip_runtime.h>

// ---------------------------------------------------------------------------
// HAN forward on MI355X.
// S=16 sents, B=32 batch, T=64 tokens, E=H=256, 2H=512, NC=50, V=50000.
// R3: gru kernels -> 1024 thr (4 waves/SIMD); attn_score rewritten with
// A-in-registers + LDS-staged W (was re-streaming A 32x); small-kernel fixes.
// ---------------------------------------------------------------------------

typedef float  f32x4  __attribute__((ext_vector_type(4)));
typedef int    i32x4  __attribute__((ext_vector_type(4)));
typedef __bf16 bf16x8 __attribute__((ext_vector_type(8)));

#define DEVINL static __device__ __forceinline__

DEVINL unsigned short f2bf(float f) {          // RNE float->bf16
    unsigned int x = __builtin_bit_cast(unsigned int, f);
    x = x + 0x7fffu + ((x >> 16) & 1u);
    return (unsigned short)(x >> 16);
}
DEVINL float bf2f(unsigned short u) {
    unsigned int x = ((unsigned int)u) << 16;
    return __builtin_bit_cast(float, x);
}
DEVINL float sigm(float x) { return __builtin_amdgcn_rcpf(1.f + __expf(-x)); }
DEVINL float tanh_(float x) {
    x = fminf(fmaxf(x, -20.f), 20.f);
    float e = __expf(-2.f * x);
    return (1.f - e) * __builtin_amdgcn_rcpf(1.f + e);
}
DEVINL void mfma16(f32x4& acc, i32x4 a, i32x4 b) {
    acc = __builtin_amdgcn_mfma_f32_16x16x32_bf16(
        __builtin_bit_cast(bf16x8, a), __builtin_bit_cast(bf16x8, b), acc, 0, 0, 0);
}
DEVINL f32x4 zero4() { f32x4 v = {0.f, 0.f, 0.f, 0.f}; return v; }

// ---- workspace layout (bytes, all 256-aligned) ----------------------------
#define O_WPWF    ((size_t)0)         // word comb fwd  [1024n][512k] bf16 frag
#define O_WPWB    ((size_t)1048576)
#define O_WPSGIH  ((size_t)2097152)   // sent Wih cat   [1536n][512k]
#define O_WPSHHF  ((size_t)3670016)   // sent Whh fwd   [768n][256k]
#define O_WPSHHB  ((size_t)4063232)
#define O_WPWW    ((size_t)4456448)   // word_W^T       [512n][512k]
#define O_WPSW    ((size_t)4980736)   // sent_W^T
#define O_BIASWF  ((size_t)5505024)   // word bias comb [4][256] f32
#define O_BIASWB  ((size_t)5509120)
#define O_BIHCAT  ((size_t)5513216)   // sent bih cat [1536] f32
#define O_WOUT    ((size_t)5519360)   // word_out bf16 A-frag, rows 32768 x 512
#define O_SCORESW ((size_t)39073792)  // word scores f32 [32768]
#define O_SSFRAG  ((size_t)39204864)  // s bf16 A-frag, rows 512 x 512
#define O_XPSENT  ((size_t)39729152)  // xp_sent f32 [512][1536]
#define O_SOFRAG  ((size_t)42874880)  // sent_out bf16 A-frag, rows 512 x 512
#define O_SCORESS ((size_t)43399168)  // sent scores f32 [512]
#define WS_NEED   ((size_t)43401216)

// ---------------------------------------------------------------------------
// prep: all weight repacks.  Fragment-linear layout for B operands:
//   short index = ((nf*KF + kf)*64 + lane)*8 + j,
//   n = nf*16 + (lane&15),  k = kf*32 + (lane>>4)*8 + j,  value = B(k, n).
// ---------------------------------------------------------------------------
__global__ void k_prep(const float* wihf, const float* whhf,
                       const float* wihb, const float* whhb,
                       const float* sgihf, const float* sgihb,
                       const float* sghhf, const float* sghhb,
                       const float* wordW, const float* sentW,
                       const float* bihf, const float* bhhf,
                       const float* bihb, const float* bhhb,
                       const float* sgbihf, const float* sgbihb,
                       unsigned short* Wpwf, unsigned short* Wpwb,
                       unsigned short* Wpsgih,
                       unsigned short* WpshhF, unsigned short* WpshhB,
                       unsigned short* WpwW, unsigned short* WpsW,
                       float* biasWf, float* biasWb, float* bihCat)
{
    const int tid0 = blockIdx.x * blockDim.x + threadIdx.x;
    const int nth  = gridDim.x * blockDim.x;

    // A) word combined [r|z|xn|hn] x [e(256)|h(256)], both dirs. KF=16.
    for (int idx = tid0; idx < 2 * 524288; idx += nth) {
        int d = idx >> 19, sidx = idx & 524287;
        int j = sidx & 7, chunk = sidx >> 3;
        int lane = chunk & 63, nk = chunk >> 6;
        int kf = nk & 15, nf = nk >> 4;
        int n = nf * 16 + (lane & 15);
        int k = kf * 32 + (lane >> 4) * 8 + j;
        const float* Wih = d ? wihb : wihf;
        const float* Whh = d ? whhb : whhf;
        int g4 = n >> 8, jj = n & 255;
        float v = 0.f;
        if (k < 256) {
            if (g4 == 0) v = Wih[jj * 256 + k];
            else if (g4 == 1) v = Wih[(256 + jj) * 256 + k];
            else if (g4 == 2) v = Wih[(512 + jj) * 256 + k];
        } else {
            int kk = k - 256;
            if (g4 == 0) v = Whh[jj * 256 + kk];
            else if (g4 == 1) v = Whh[(256 + jj) * 256 + kk];
            else if (g4 == 3) v = Whh[(512 + jj) * 256 + kk];
        }
        (d ? Wpwb : Wpwf)[sidx] = f2bf(v);
    }
    // B) sentence Wih cat [1536n][512k]. KF=16.
    for (int idx = tid0; idx < 786432; idx += nth) {
        int j = idx & 7, chunk = idx >> 3;
        int lane = chunk & 63, nk = chunk >> 6;
        int kf = nk & 15, nf = nk >> 4;
        int n = nf * 16 + (lane & 15);
        int k = kf * 32 + (lane >> 4) * 8 + j;
        float v = (n < 768) ? sgihf[n * 512 + k] : sgihb[(n - 768) * 512 + k];
        Wpsgih[idx] = f2bf(v);
    }
    // C) sentence Whh f/b [768n][256k]. KF=8.
    for (int idx = tid0; idx < 2 * 196608; idx += nth) {
        int d = idx >= 196608;
        int sidx = d ? idx - 196608 : idx;
        int j = sidx & 7, chunk = sidx >> 3;
        int lane = chunk & 63, nk = chunk >> 6;
        int kf = nk & 7, nf = nk >> 3;
        int n = nf * 16 + (lane & 15);
        int k = kf * 32 + (lane >> 4) * 8 + j;
        float v = (d ? sghhb : sghhf)[n * 256 + k];
        (d ? WpshhB : WpshhF)[sidx] = f2bf(v);
    }
    // D) word_W / sent_W transposed: B(k,n) = W[k*512+n]. KF=16.
    for (int idx = tid0; idx < 2 * 262144; idx += nth) {
        int d = idx >> 18, sidx = idx & 262143;
        int j = sidx & 7, chunk = sidx >> 3;
        int lane = chunk & 63, nk = chunk >> 6;
        int kf = nk & 15, nf = nk >> 4;
        int n = nf * 16 + (lane & 15);
        int k = kf * 32 + (lane >> 4) * 8 + j;
        float v = (d ? sentW : wordW)[k * 512 + n];
        (d ? WpsW : WpwW)[sidx] = f2bf(v);
    }
    // E) word bias comb: [r: bih+bhh][z: bih+bhh][xn: bih][hn: bhh]
    for (int idx = tid0; idx < 2048; idx += nth) {
        int d = idx >> 10, i = idx & 1023;
        int g4 = i >> 8, j = i & 255;
        const float* bi = d ? bihb : bihf;
        const float* bh = d ? bhhb : bhhf;
        float v = (g4 == 0) ? bi[j] + bh[j]
                : (g4 == 1) ? bi[256 + j] + bh[256 + j]
                : (g4 == 2) ? bi[512 + j] : bh[512 + j];
        (d ? biasWb : biasWf)[i] = v;
    }
    // F) sentence bih cat
    for (int idx = tid0; idx < 1536; idx += nth)
        bihCat[idx] = (idx < 768) ? sgbihf[idx] : sgbihb[idx - 768];
}

// ---------------------------------------------------------------------------
// word bi-GRU: one WG (1024 thr, 16 waves) per (sentence, dir).
// A=[e_t | h] in LDS (XOR-swizzled, double-buffered), h fp32 in registers,
// fused 4-gate GEMM K=512. Wave w owns n-column w of each gate group:
// 3 B-frag loads + 6 MFMAs per kf, 3-deep register ring prefetch.
// ---------------------------------------------------------------------------
DEVINL void prefetchE(unsigned short (*Ab)[512], const int* xg, const float* embed,
                      int s, int t, int tid)
{
    const int brow = tid >> 5, c = tid & 31;          // 32 rows x 32 thr
    const int tok = xg[(s * 32 + brow) * 64 + t];
    const f32x4* src = (const f32x4*)(embed + (size_t)tok * 256) + c * 2;
    f32x4 f0 = src[0], f1 = src[1];
    i32x4 pk;
    pk.x = (int)((unsigned)f2bf(f0.x) | ((unsigned)f2bf(f0.y) << 16));
    pk.y = (int)((unsigned)f2bf(f0.z) | ((unsigned)f2bf(f0.w) << 16));
    pk.z = (int)((unsigned)f2bf(f1.x) | ((unsigned)f2bf(f1.y) << 16));
    pk.w = (int)((unsigned)f2bf(f1.z) | ((unsigned)f2bf(f1.w) << 16));
    int kbyte = (c * 16) ^ ((brow & 7) << 4);
    *(i32x4*)((char*)&Ab[brow][0] + kbyte) = pk;
}

__global__ __launch_bounds__(1024, 4)
void k_gru_word(const int* xg, const float* embed, const float* stateW,
                const unsigned short* Wpwf_u, const unsigned short* Wpwb_u,
                const float* biasWf, const float* biasWb,
                unsigned short* wout)
{
    __shared__ unsigned short Abuf[2][32][512];   // 64 KiB

    const int tid = threadIdx.x, lane = tid & 63, w = tid >> 6;   // w 0..15
    const int cid = blockIdx.x, s = cid >> 1, dir = cid & 1;
    const i32x4* Wp = (const i32x4*)(dir ? Wpwb_u : Wpwf_u);
    const float* bias = dir ? biasWb : biasWf;

    const int j = w * 16 + (lane & 15);   // this wave's hidden column
    float hreg[2][4];
#pragma unroll
    for (int mf = 0; mf < 2; ++mf)
#pragma unroll
        for (int i = 0; i < 4; ++i) {
            int b = mf * 16 + (lane >> 4) * 4 + i;
            float h0 = stateW[dir * 8192 + b * 256 + j];
            hreg[mf][i] = h0;
            int byteoff = ((256 + j) * 2) ^ ((b & 7) << 4);
            *(unsigned short*)((char*)&Abuf[0][b][0] + byteoff) = f2bf(h0);
        }
    const int tfirst = dir ? 63 : 0;
    prefetchE(Abuf[0], xg, embed, s, tfirst, tid);

    const float br = bias[j], bz = bias[256 + j];
    const float bxn = bias[512 + j], bhn = bias[768 + j];

    for (int ti = 0; ti < 64; ++ti) {
        __syncthreads();
        const int t = dir ? 63 - ti : ti;
        const int cur = ti & 1, nxt = cur ^ 1;
        if (ti < 63) prefetchE(Abuf[nxt], xg, embed, s, dir ? t - 1 : t + 1, tid);

        f32x4 acc[4][2];
#pragma unroll
        for (int g = 0; g < 4; ++g) { acc[g][0] = zero4(); acc[g][1] = zero4(); }

        i32x4 bbuf[3][3];
#define LOADB_W(KF, DST)                                                     \
        {                                                                    \
            const int gX = ((KF) < 8) ? 32 : 48;                             \
            DST[0] = Wp[((0 + w)  * 16 + (KF)) * 64 + lane];                 \
            DST[1] = Wp[((16 + w) * 16 + (KF)) * 64 + lane];                 \
            DST[2] = Wp[((gX + w) * 16 + (KF)) * 64 + lane];                 \
        }
        LOADB_W(0, bbuf[0]);
        LOADB_W(1, bbuf[1]);

#pragma unroll
        for (int kf = 0; kf < 16; ++kf) {
            if (kf < 14) LOADB_W(kf + 2, bbuf[(kf + 2) % 3]);
            const int row0 = lane & 15;
            const int boff = (kf * 64 + (lane >> 4) * 16) ^ ((row0 & 7) << 4);
            i32x4 a0 = *(const i32x4*)((const char*)&Abuf[cur][row0][0] + boff);
            i32x4 a1 = *(const i32x4*)((const char*)&Abuf[cur][16 + row0][0] + boff);
            const i32x4* bc = bbuf[kf % 3];
            mfma16(acc[0][0], a0, bc[0]); mfma16(acc[0][1], a1, bc[0]);
            mfma16(acc[1][0], a0, bc[1]); mfma16(acc[1][1], a1, bc[1]);
            if (kf < 8) { mfma16(acc[2][0], a0, bc[2]);
                          mfma16(acc[2][1], a1, bc[2]); }
            else        { mfma16(acc[3][0], a0, bc[2]);
                          mfma16(acc[3][1], a1, bc[2]); }
        }
#undef LOADB_W

#pragma unroll
        for (int mf = 0; mf < 2; ++mf)
#pragma unroll
            for (int i = 0; i < 4; ++i) {
                const int b = mf * 16 + (lane >> 4) * 4 + i;
                float rv = sigm(acc[0][mf][i] + br);
                float zv = sigm(acc[1][mf][i] + bz);
                float nv = tanh_(acc[2][mf][i] + bxn +
                                 rv * (acc[3][mf][i] + bhn));
                float hnew = (1.f - zv) * nv + zv * hreg[mf][i];
                hreg[mf][i] = hnew;
                unsigned short hb = f2bf(hnew);
                int byteoff = ((256 + j) * 2) ^ ((b & 7) << 4);
                *(unsigned short*)((char*)&Abuf[nxt][b][0] + byteoff) = hb;
                int r = (s * 64 + t) * 32 + b;
                int hcol = dir * 256 + j;
                wout[(((r >> 4) * 16 + (hcol >> 5)) * 64 + (r & 15) +
                      ((hcol >> 3) & 3) * 16) * 8 + (hcol & 7)] = hb;
            }
    }
}

// ---------------------------------------------------------------------------
// attention scores v2: score[r] = sum_n tanh((A@W)[r,n] + b[n]) * proj[n]
// A-frags held in registers (read once); W staged per-nf into LDS dbuf.
// 8 rblk per WG (1/wave), 512 thr.
// ---------------------------------------------------------------------------
__global__ __launch_bounds__(512, 4)
void k_attn_score2(const unsigned short* Afrag_u, const unsigned short* Wp_u,
                   const float* wb, const float* wp, float* scores)
{
    __shared__ i32x4 Wl[2][16][64];   // 32 KiB
    const int tid = threadIdx.x, lane = tid & 63, w = tid >> 6;
    const int rblk = blockIdx.x * 8 + w;
    const i32x4* A = (const i32x4*)Afrag_u;
    const i32x4* Wg = (const i32x4*)Wp_u;

    i32x4 a[16];
#pragma unroll
    for (int kf = 0; kf < 16; ++kf) a[kf] = A[(rblk * 16 + kf) * 64 + lane];

    i32x4* wl0 = &Wl[0][0][0];
    i32x4* wl1 = &Wl[1][0][0];
    // stage nf=0
    wl0[tid] = Wg[tid]; wl0[tid + 512] = Wg[tid + 512];

    float partial[4] = {};
    for (int nf = 0; nf < 32; ++nf) {
        __syncthreads();
        if (nf < 31) {
            i32x4* dst = (nf & 1) ? wl0 : wl1;
            dst[tid]       = Wg[(nf + 1) * 1024 + tid];
            dst[tid + 512] = Wg[(nf + 1) * 1024 + tid + 512];
        }
        const i32x4* cur = (nf & 1) ? wl1 : wl0;
        f32x4 acc0 = zero4(), acc1 = zero4();
#pragma unroll
        for (int kf = 0; kf < 16; kf += 2) {
            mfma16(acc0, a[kf],     cur[kf * 64 + lane]);
            mfma16(acc1, a[kf + 1], cur[(kf + 1) * 64 + lane]);
        }
        const int n = nf * 16 + (lane & 15);
        const float wbn = wb[n], wpn = wp[n];
#pragma unroll
        for (int i = 0; i < 4; ++i)
            partial[i] += tanh_(acc0[i] + acc1[i] + wbn) * wpn;
    }
#pragma unroll
    for (int i = 0; i < 4; ++i) {
        float v = partial[i];
        v += __shfl_xor(v, 1); v += __shfl_xor(v, 2);
        v += __shfl_xor(v, 4); v += __shfl_xor(v, 8);
        if ((lane & 15) == 0)
            scores[rblk * 16 + (lane >> 4) * 4 + i] = v;
    }
}

// small-row variant (sentence scores, 512 rows): a[16] hoisted to registers.
__global__ void k_attn_score_small(const unsigned short* Afrag_u,
                                   const unsigned short* Wp_u,
                                   const float* wb, const float* wp, float* scores)
{
    const int tid = threadIdx.x, lane = tid & 63, w = tid >> 6;
    const int rblk = blockIdx.x * 4 + w;
    const i32x4* A = (const i32x4*)Afrag_u;
    const i32x4* Wp = (const i32x4*)Wp_u;
    i32x4 a[16];
#pragma unroll
    for (int kf = 0; kf < 16; ++kf) a[kf] = A[(rblk * 16 + kf) * 64 + lane];

    float partial[4] = {};
    for (int nf = 0; nf < 32; ++nf) {
        f32x4 acc0 = zero4(), acc1 = zero4();
#pragma unroll
        for (int kf = 0; kf < 16; kf += 2) {
            mfma16(acc0, a[kf],     Wp[(nf * 16 + kf) * 64 + lane]);
            mfma16(acc1, a[kf + 1], Wp[(nf * 16 + kf + 1) * 64 + lane]);
        }
        const int n = nf * 16 + (lane & 15);
        const float wbn = wb[n], wpn = wp[n];
#pragma unroll
        for (int i = 0; i < 4; ++i)
            partial[i] += tanh_(acc0[i] + acc1[i] + wbn) * wpn;
    }
#pragma unroll
    for (int i = 0; i < 4; ++i) {
        float v = partial[i];
        v += __shfl_xor(v, 1); v += __shfl_xor(v, 2);
        v += __shfl_xor(v, 4); v += __shfl_xor(v, 8);
        if ((lane & 15) == 0)
            scores[rblk * 16 + (lane >> 4) * 4 + i] = v;
    }
}

// softmax over T + weighted sum -> s (bf16 A-frag layout, rows r2=s*32+b)
__global__ void k_word_pool(const float* scores, const unsigned short* wout,
                            unsigned short* ssFrag)
{
    __shared__ float aL[64];
    const int l = threadIdx.x;                 // 64 threads
    const int bid = blockIdx.x;                // 0..511
    const int s = bid >> 5, b = bid & 31;
    float sc = scores[s * 2048 + l * 32 + b];
    float m = sc;
#pragma unroll
    for (int d = 1; d < 64; d <<= 1) m = fmaxf(m, __shfl_xor(m, d));
    float e = __expf(sc - m), sum = e;
#pragma unroll
    for (int d = 1; d < 64; d <<= 1) sum += __shfl_xor(sum, d);
    aL[l] = e * __builtin_amdgcn_rcpf(sum);
    __syncthreads();

    float acc[8] = {};
    const i32x4* WO = (const i32x4*)wout;
    for (int t = 0; t < 64; ++t) {
        float at = aL[t];
        int cidx = ((s * 128 + t * 2 + (b >> 4)) * 16 + (l >> 2)) * 64 +
                   (b & 15) + (l & 3) * 16;
        i32x4 ch = WO[cidx];
        acc[0] += at * bf2f((unsigned short)((unsigned)ch.x & 0xffffu));
        acc[1] += at * bf2f((unsigned short)((unsigned)ch.x >> 16));
        acc[2] += at * bf2f((unsigned short)((unsigned)ch.y & 0xffffu));
        acc[3] += at * bf2f((unsigned short)((unsigned)ch.y >> 16));
        acc[4] += at * bf2f((unsigned short)((unsigned)ch.z & 0xffffu));
        acc[5] += at * bf2f((unsigned short)((unsigned)ch.z >> 16));
        acc[6] += at * bf2f((unsigned short)((unsigned)ch.w & 0xffffu));
        acc[7] += at * bf2f((unsigned short)((unsigned)ch.w >> 16));
    }
    i32x4 pk;
    pk.x = (int)((unsigned)f2bf(acc[0]) | ((unsigned)f2bf(acc[1]) << 16));
    pk.y = (int)((unsigned)f2bf(acc[2]) | ((unsigned)f2bf(acc[3]) << 16));
    pk.z = (int)((unsigned)f2bf(acc[4]) | ((unsigned)f2bf(acc[5]) << 16));
    pk.w = (int)((unsigned)f2bf(acc[6]) | ((unsigned)f2bf(acc[7]) << 16));
    const int r2 = s * 32 + b;
    int cidx2 = ((r2 >> 4) * 16 + (l >> 2)) * 64 + (r2 & 15) + (l & 3) * 16;
    ((i32x4*)ssFrag)[cidx2] = pk;
}

// xp_sent[row][n] = (s @ sg_Wih_cat^T)[row][n] + bih_cat[n]
__global__ void k_sgih(const unsigned short* ssFrag_u, const unsigned short* Wp_u,
                       const float* bihCat, float* xpSent)
{
    const int tid = threadIdx.x, lane = tid & 63, w = tid >> 6;
    const int rblk = blockIdx.x, ncl = blockIdx.y;
    const i32x4* A = (const i32x4*)ssFrag_u;
    const i32x4* Wp = (const i32x4*)Wp_u;
    i32x4 a[16];
#pragma unroll
    for (int kf = 0; kf < 16; ++kf) a[kf] = A[(rblk * 16 + kf) * 64 + lane];
#pragma unroll
    for (int nfl = 0; nfl < 4; ++nfl) {
        const int nfg = ncl * 16 + w * 4 + nfl;
        f32x4 acc = zero4();
#pragma unroll
        for (int kf = 0; kf < 16; ++kf)
            mfma16(acc, a[kf], Wp[(nfg * 16 + kf) * 64 + lane]);
        const int n = nfg * 16 + (lane & 15);
        const float bb = bihCat[n];
#pragma unroll
        for (int i = 0; i < 4; ++i) {
            int row = rblk * 16 + (lane >> 4) * 4 + i;
            xpSent[row * 1536 + n] = acc[i] + bb;
        }
    }
}

// sentence bi-GRU: 2 WGs (1024 thr, 16 waves), 16 steps, K=256 recurrent GEMM.
__global__ __launch_bounds__(1024, 4)
void k_gru_sent(const float* stateS, const unsigned short* WpF_u,
                const unsigned short* WpB_u, const float* bhhf, const float* bhhb,
                const float* xpSent, unsigned short* soFrag)
{
    __shared__ unsigned short Abuf[2][32][256];   // 32 KiB
    const int tid = threadIdx.x, lane = tid & 63, w = tid >> 6;  // w 0..15
    const int dir = blockIdx.x;
    const i32x4* Wp = (const i32x4*)(dir ? WpB_u : WpF_u);
    const float* bhh = dir ? bhhb : bhhf;

    const int j = w * 16 + (lane & 15);
    float hreg[2][4];
#pragma unroll
    for (int mf = 0; mf < 2; ++mf)
#pragma unroll
        for (int i = 0; i < 4; ++i) {
            int b = mf * 16 + (lane >> 4) * 4 + i;
            float h0 = stateS[dir * 8192 + b * 256 + j];
            hreg[mf][i] = h0;
            int byteoff = (j * 2) ^ ((b & 7) << 4);
            *(unsigned short*)((char*)&Abuf[0][b][0] + byteoff) = f2bf(h0);
        }
    const float bhr = bhh[j], bhz = bhh[256 + j], bhn = bhh[512 + j];

    for (int si = 0; si < 16; ++si) {
        __syncthreads();
        const int s = dir ? 15 - si : si;
        const int cur = si & 1, nxt = cur ^ 1;
        f32x4 acc[3][2];
#pragma unroll
        for (int g = 0; g < 3; ++g) { acc[g][0] = zero4(); acc[g][1] = zero4(); }

        i32x4 bbuf[3][3];
#define LOADB_S(KF, DST)                                                     \
        {                                                                    \
            DST[0] = Wp[((0 + w)  * 8 + (KF)) * 64 + lane];                  \
            DST[1] = Wp[((16 + w) * 8 + (KF)) * 64 + lane];                  \
            DST[2] = Wp[((32 + w) * 8 + (KF)) * 64 + lane];                  \
        }
        LOADB_S(0, bbuf[0]);
        LOADB_S(1, bbuf[1]);
#pragma unroll
        for (int kf = 0; kf < 8; ++kf) {
            if (kf < 6) LOADB_S(kf + 2, bbuf[(kf + 2) % 3]);
            const int row0 = lane & 15;
            const int boff = (kf * 64 + (lane >> 4) * 16) ^ ((row0 & 7) << 4);
            i32x4 a0 = *(const i32x4*)((const char*)&Abuf[cur][row0][0] + boff);
            i32x4 a1 = *(const i32x4*)((const char*)&Abuf[cur][16 + row0][0] + boff);
            const i32x4* bc = bbuf[kf % 3];
            mfma16(acc[0][0], a0, bc[0]); mfma16(acc[0][1], a1, bc[0]);
            mfma16(acc[1][0], a0, bc[1]); mfma16(acc[1][1], a1, bc[1]);
            mfma16(acc[2][0], a0, bc[2]); mfma16(acc[2][1], a1, bc[2]);
        }
#undef LOADB_S

#pragma unroll
        for (int mf = 0; mf < 2; ++mf)
#pragma unroll
            for (int i = 0; i < 4; ++i) {
                const int b = mf * 16 + (lane >> 4) * 4 + i;
                const float* xp = xpSent + ((s * 32 + b) * 1536 + dir * 768);
                float rv = sigm(xp[j] + acc[0][mf][i] + bhr);
                float zv = sigm(xp[256 + j] + acc[1][mf][i] + bhz);
                float nv = tanh_(xp[512 + j] + rv * (acc[2][mf][i] + bhn));
                float hnew = (1.f - zv) * nv + zv * hreg[mf][i];
                hreg[mf][i] = hnew;
                unsigned short hb = f2bf(hnew);
                int byteoff = (j * 2) ^ ((b & 7) << 4);
                *(unsigned short*)((char*)&Abuf[nxt][b][0] + byteoff) = hb;
                int r2 = s * 32 + b, hcol = dir * 256 + j;
                soFrag[(((r2 >> 4) * 16 + (hcol >> 5)) * 64 + (r2 & 15) +
                        ((hcol >> 3) & 3) * 16) * 8 + (hcol & 7)] = hb;
            }
    }
}

// sentence softmax over S + pool + final linear (256 thr, k-split matmul)
__global__ void k_sent_pool_fin(const float* scoresS, const unsigned short* soFrag,
                                const float* finW, const float* finb, float* out)
{
    __shared__ float aL[16];
    __shared__ float pooled[512];
    __shared__ float part[4][64];
    const int l = threadIdx.x;   // 0..255
    const int b = blockIdx.x;    // 0..31

    if (l < 64) {
        float sc = (l < 16) ? scoresS[l * 32 + b] : -1e30f;
        float m = sc;
#pragma unroll
        for (int d = 1; d < 16; d <<= 1) m = fmaxf(m, __shfl_xor(m, d));
        float e = (l < 16) ? __expf(sc - m) : 0.f;
        float sum = e;
#pragma unroll
        for (int d = 1; d < 16; d <<= 1) sum += __shfl_xor(sum, d);
        if (l < 16) aL[l] = e * __builtin_amdgcn_rcpf(sum);
    }
    __syncthreads();

    if (l < 64) {
        float acc[8] = {};
        const i32x4* SO = (const i32x4*)soFrag;
        for (int si = 0; si < 16; ++si) {
            float as = aL[si];
            int r2 = si * 32 + b;
            int cidx = ((r2 >> 4) * 16 + (l >> 2)) * 64 + (r2 & 15) + (l & 3) * 16;
            i32x4 ch = SO[cidx];
            acc[0] += as * bf2f((unsigned short)((unsigned)ch.x & 0xffffu));
            acc[1] += as * bf2f((unsigned short)((unsigned)ch.x >> 16));
            acc[2] += as * bf2f((unsigned short)((unsigned)ch.y & 0xffffu));
            acc[3] += as * bf2f((unsigned short)((unsigned)ch.y >> 16));
            acc[4] += as * bf2f((unsigned short)((unsigned)ch.z & 0xffffu));
            acc[5] += as * bf2f((unsigned short)((unsigned)ch.z >> 16));
            acc[6] += as * bf2f((unsigned short)((unsigned)ch.w & 0xffffu));
            acc[7] += as * bf2f((unsigned short)((unsigned)ch.w >> 16));
        }
#pragma unroll
        for (int q = 0; q < 8; ++q) pooled[l * 8 + q] = acc[q];
    }
    __syncthreads();
    {
        const int c = l & 63, kq = l >> 6;
        float v = 0.f;
        if (c < 50) {
            const float* wrow = finW + c * 512 + kq * 128;
            const float* pp = pooled + kq * 128;
            for (int k = 0; k < 128; ++k) v += pp[k] * wrow[k];
        }
        part[kq][c] = v;
    }
    __syncthreads();
    if (l < 50)
        out[b * 50 + l] = finb[l] + part[0][l] + part[1][l] + part[2][l] + part[3][l];
}

// ---------------------------------------------------------------------------
extern "C" void kernel_launch(void* const* d_in, const int* in_sizes, int n_in,
                              void* d_out, int out_size, void* d_ws, size_t ws_size,
                              hipStream_t stream)
{
    if (ws_size < WS_NEED) return;   // avoid OOB scribbling if ws too small

    const int*   x      = (const int*)d_in[0];
    const float* embed  = (const float*)d_in[1];
    const float* wgWihF = (const float*)d_in[2];
    const float* wgWhhF = (const float*)d_in[3];
    const float* wgBihF = (const float*)d_in[4];
    const float* wgBhhF = (const float*)d_in[5];
    const float* wgWihB = (const float*)d_in[6];
    const float* wgWhhB = (const float*)d_in[7];
    const float* wgBihB = (const float*)d_in[8];
    const float* wgBhhB = (const float*)d_in[9];
    const float* wordW  = (const float*)d_in[10];
    const float* wordB  = (const float*)d_in[11];
    const float* wordP  = (const float*)d_in[12];
    const float* sgWihF = (const float*)d_in[13];
    const float* sgWhhF = (const float*)d_in[14];
    const float* sgBihF = (const float*)d_in[15];
    const float* sgBhhF = (const float*)d_in[16];
    const float* sgWihB = (const float*)d_in[17];
    const float* sgWhhB = (const float*)d_in[18];
    const float* sgBihB = (const float*)d_in[19];
    const float* sgBhhB = (const float*)d_in[20];
    const float* sentWm = (const float*)d_in[21];
    const float* sentB  = (const float*)d_in[22];
    const float* sentP  = (const float*)d_in[23];
    const float* finW   = (const float*)d_in[24];
    const float* finB   = (const float*)d_in[25];
    const float* stateW = (const float*)d_in[26];
    const float* stateS = (const float*)d_in[27];

    char* ws = (char*)d_ws;
    unsigned short* Wpwf   = (unsigned short*)(ws + O_WPWF);
    unsigned short* Wpwb   = (unsigned short*)(ws + O_WPWB);
    unsigned short* Wpsgih = (unsigned short*)(ws + O_WPSGIH);
    unsigned short* WpshhF = (unsigned short*)(ws + O_WPSHHF);
    unsigned short* WpshhB = (unsigned short*)(ws + O_WPSHHB);
    unsigned short* WpwW   = (unsigned short*)(ws + O_WPWW);
    unsigned short* WpsW   = (unsigned short*)(ws + O_WPSW);
    float* biasWf  = (float*)(ws + O_BIASWF);
    float* biasWb  = (float*)(ws + O_BIASWB);
    float* bihCat  = (float*)(ws + O_BIHCAT);
    unsigned short* wout   = (unsigned short*)(ws + O_WOUT);
    float* scoresW = (float*)(ws + O_SCORESW);
    unsigned short* ssFrag = (unsigned short*)(ws + O_SSFRAG);
    float* xpSent  = (float*)(ws + O_XPSENT);
    unsigned short* soFrag = (unsigned short*)(ws + O_SOFRAG);
    float* scoresS = (float*)(ws + O_SCORESS);

    k_prep<<<512, 256, 0, stream>>>(wgWihF, wgWhhF, wgWihB, wgWhhB,
                                    sgWihF, sgWihB, sgWhhF, sgWhhB,
                                    wordW, sentWm,
                                    wgBihF, wgBhhF, wgBihB, wgBhhB,
                                    sgBihF, sgBihB,
                                    Wpwf, Wpwb, Wpsgih, WpshhF, WpshhB,
                                    WpwW, WpsW, biasWf, biasWb, bihCat);

    k_gru_word<<<32, 1024, 0, stream>>>(x, embed, stateW, Wpwf, Wpwb,
                                        biasWf, biasWb, wout);

    k_attn_score2<<<256, 512, 0, stream>>>(wout, WpwW, wordB, wordP, scoresW);
    k_word_pool<<<512, 64, 0, stream>>>(scoresW, wout, ssFrag);

    k_sgih<<<dim3(32, 6), 256, 0, stream>>>(ssFrag, Wpsgih, bihCat, xpSent);
    k_gru_sent<<<2, 1024, 0, stream>>>(stateS, WpshhF, WpshhB, sgBhhF, sgBhhB,
                                       xpSent, soFrag);

    k_attn_score_small<<<8, 256, 0, stream>>>(soFrag, WpsW, sentB, sentP, scoresS);
    k_sent_pool_fin<<<32, 256, 0, stream>>>(scoresS, soFrag, finW, finB,
                                            (float*)d_out);
}

// Round 5
// 449.402 us; speedup vs baseline: 6.8185x; 2.7012x over previous
//
#include <hip/hip_runtime.h>

// ---------------------------------------------------------------------------
// HAN forward on MI355X.
// S=16 sents, B=32 batch, T=64 tokens, E=H=256, 2H=512, NC=50, V=50000.
// R4: PATH A (if ws >= ~170MB): precompute xp = x@Wih+biases as a full-chip
// GEMM (k_xpw), then word-GRU with Whh REGISTER-RESIDENT (64 WGs, b-split,
// zero in-loop weight traffic). PATH B fallback: R4 streaming kernels.
// Sentence GRU register-resident in both paths.
// ---------------------------------------------------------------------------

typedef float  f32x4  __attribute__((ext_vector_type(4)));
typedef int    i32x4  __attribute__((ext_vector_type(4)));
typedef __bf16 bf16x8 __attribute__((ext_vector_type(8)));

#define DEVINL static __device__ __forceinline__

DEVINL unsigned short f2bf(float f) {          // RNE float->bf16
    unsigned int x = __builtin_bit_cast(unsigned int, f);
    x = x + 0x7fffu + ((x >> 16) & 1u);
    return (unsigned short)(x >> 16);
}
DEVINL float bf2f(unsigned short u) {
    unsigned int x = ((unsigned int)u) << 16;
    return __builtin_bit_cast(float, x);
}
DEVINL float sigm(float x) { return __builtin_amdgcn_rcpf(1.f + __expf(-x)); }
DEVINL float tanh_(float x) {
    x = fminf(fmaxf(x, -20.f), 20.f);
    float e = __expf(-2.f * x);
    return (1.f - e) * __builtin_amdgcn_rcpf(1.f + e);
}
DEVINL void mfma16(f32x4& acc, i32x4 a, i32x4 b) {
    acc = __builtin_amdgcn_mfma_f32_16x16x32_bf16(
        __builtin_bit_cast(bf16x8, a), __builtin_bit_cast(bf16x8, b), acc, 0, 0, 0);
}
DEVINL f32x4 zero4() { f32x4 v = {0.f, 0.f, 0.f, 0.f}; return v; }
DEVINL void gload16(const void* gsrc, void* ldst) {
    __builtin_amdgcn_global_load_lds(
        (const __attribute__((address_space(1))) unsigned int*)gsrc,
        (__attribute__((address_space(3))) unsigned int*)ldst, 16, 0, 0);
}

// ---- workspace layout (bytes, all 256-aligned) ----------------------------
#define O_WPWF    ((size_t)0)         // word comb fwd  [1024n][512k] bf16 frag
#define O_WPWB    ((size_t)1048576)
#define O_WPSGIH  ((size_t)2097152)   // sent Wih cat   [1536n][512k]
#define O_WPSHHF  ((size_t)3670016)   // sent Whh fwd   [768n][256k]
#define O_WPSHHB  ((size_t)4063232)
#define O_WPWW    ((size_t)4456448)   // word_W^T       [512n][512k]
#define O_WPSW    ((size_t)4980736)   // sent_W^T
#define O_BIASWF  ((size_t)5505024)   // word bias comb [4][256] f32
#define O_BIASWB  ((size_t)5509120)
#define O_BIHCAT  ((size_t)5513216)   // sent bih(+bhh r,z) cat [1536] f32
#define O_WOUT    ((size_t)5519360)   // word_out bf16 A-frag, rows 32768 x 512
#define O_SCORESW ((size_t)39073792)  // word scores f32 [32768]
#define O_SSFRAG  ((size_t)39204864)  // s bf16 A-frag, rows 512 x 512
#define O_XPSENT  ((size_t)39729152)  // xp_sent f32 [dir][bh][s][3][256][16]
#define O_SOFRAG  ((size_t)42874880)  // sent_out bf16 A-frag, rows 512 x 512
#define O_SCORESS ((size_t)43399168)  // sent scores f32 [512]
#define WS_NEED_B ((size_t)43401216)
#define O_EMB16   ((size_t)43401216)  // embed bf16 [50000][256]
#define O_XPW     ((size_t)69001216)  // word xp bf16 [s][dir][bh][t][3][256][16]
#define WS_NEED_A ((size_t)169664512)

// ---------------------------------------------------------------------------
// prep: weight repacks. Fragment-linear layout for B operands:
//   short index = ((nf*KF + kf)*64 + lane)*8 + j,
//   n = nf*16 + (lane&15),  k = kf*32 + (lane>>4)*8 + j,  value = B(k, n).
// ---------------------------------------------------------------------------
__global__ void k_prep(const float* wihf, const float* whhf,
                       const float* wihb, const float* whhb,
                       const float* sgihf, const float* sgihb,
                       const float* sghhf, const float* sghhb,
                       const float* wordW, const float* sentW,
                       const float* bihf, const float* bhhf,
                       const float* bihb, const float* bhhb,
                       const float* sgbihf, const float* sgbihb,
                       const float* sgbhhf, const float* sgbhhb,
                       const float* embed,
                       unsigned short* Wpwf, unsigned short* Wpwb,
                       unsigned short* Wpsgih,
                       unsigned short* WpshhF, unsigned short* WpshhB,
                       unsigned short* WpwW, unsigned short* WpsW,
                       float* biasWf, float* biasWb, float* bihCat,
                       unsigned short* emb16, int doEmb)
{
    const int tid0 = blockIdx.x * blockDim.x + threadIdx.x;
    const int nth  = gridDim.x * blockDim.x;

    // A) word combined [r|z|xn|hn] x [e(256)|h(256)], both dirs. KF=16.
    for (int idx = tid0; idx < 2 * 524288; idx += nth) {
        int d = idx >> 19, sidx = idx & 524287;
        int j = sidx & 7, chunk = sidx >> 3;
        int lane = chunk & 63, nk = chunk >> 6;
        int kf = nk & 15, nf = nk >> 4;
        int n = nf * 16 + (lane & 15);
        int k = kf * 32 + (lane >> 4) * 8 + j;
        const float* Wih = d ? wihb : wihf;
        const float* Whh = d ? whhb : whhf;
        int g4 = n >> 8, jj = n & 255;
        float v = 0.f;
        if (k < 256) {
            if (g4 == 0) v = Wih[jj * 256 + k];
            else if (g4 == 1) v = Wih[(256 + jj) * 256 + k];
            else if (g4 == 2) v = Wih[(512 + jj) * 256 + k];
        } else {
            int kk = k - 256;
            if (g4 == 0) v = Whh[jj * 256 + kk];
            else if (g4 == 1) v = Whh[(256 + jj) * 256 + kk];
            else if (g4 == 3) v = Whh[(512 + jj) * 256 + kk];
        }
        (d ? Wpwb : Wpwf)[sidx] = f2bf(v);
    }
    // B) sentence Wih cat [1536n][512k]. KF=16.
    for (int idx = tid0; idx < 786432; idx += nth) {
        int j = idx & 7, chunk = idx >> 3;
        int lane = chunk & 63, nk = chunk >> 6;
        int kf = nk & 15, nf = nk >> 4;
        int n = nf * 16 + (lane & 15);
        int k = kf * 32 + (lane >> 4) * 8 + j;
        float v = (n < 768) ? sgihf[n * 512 + k] : sgihb[(n - 768) * 512 + k];
        Wpsgih[idx] = f2bf(v);
    }
    // C) sentence Whh f/b [768n][256k]. KF=8.
    for (int idx = tid0; idx < 2 * 196608; idx += nth) {
        int d = idx >= 196608;
        int sidx = d ? idx - 196608 : idx;
        int j = sidx & 7, chunk = sidx >> 3;
        int lane = chunk & 63, nk = chunk >> 6;
        int kf = nk & 7, nf = nk >> 3;
        int n = nf * 16 + (lane & 15);
        int k = kf * 32 + (lane >> 4) * 8 + j;
        float v = (d ? sghhb : sghhf)[n * 256 + k];
        (d ? WpshhB : WpshhF)[sidx] = f2bf(v);
    }
    // D) word_W / sent_W transposed: B(k,n) = W[k*512+n]. KF=16.
    for (int idx = tid0; idx < 2 * 262144; idx += nth) {
        int d = idx >> 18, sidx = idx & 262143;
        int j = sidx & 7, chunk = sidx >> 3;
        int lane = chunk & 63, nk = chunk >> 6;
        int kf = nk & 15, nf = nk >> 4;
        int n = nf * 16 + (lane & 15);
        int k = kf * 32 + (lane >> 4) * 8 + j;
        float v = (d ? sentW : wordW)[k * 512 + n];
        (d ? WpsW : WpwW)[sidx] = f2bf(v);
    }
    // E) word bias comb: [r: bih+bhh][z: bih+bhh][xn: bih][hn: bhh]
    for (int idx = tid0; idx < 2048; idx += nth) {
        int d = idx >> 10, i = idx & 1023;
        int g4 = i >> 8, j = i & 255;
        const float* bi = d ? bihb : bihf;
        const float* bh = d ? bhhb : bhhf;
        float v = (g4 == 0) ? bi[j] + bh[j]
                : (g4 == 1) ? bi[256 + j] + bh[256 + j]
                : (g4 == 2) ? bi[512 + j] : bh[512 + j];
        (d ? biasWb : biasWf)[i] = v;
    }
    // F) sentence bih cat (+bhh folded for r,z; n keeps bih only)
    for (int idx = tid0; idx < 1536; idx += nth) {
        int d = idx >= 768, j = d ? idx - 768 : idx;
        const float* bi = d ? sgbihb : sgbihf;
        const float* bh = d ? sgbhhb : sgbhhf;
        bihCat[idx] = bi[j] + ((j < 512) ? bh[j] : 0.f);
    }
    // G) embed -> bf16 (PATH A only)
    if (doEmb) {
        for (int idx = tid0; idx < 3200000; idx += nth) {   // 12.8M/4
            f32x4 v = ((const f32x4*)embed)[idx];
            unsigned int lo = (unsigned)f2bf(v.x) | ((unsigned)f2bf(v.y) << 16);
            unsigned int hi = (unsigned)f2bf(v.z) | ((unsigned)f2bf(v.w) << 16);
            ((unsigned int*)emb16)[idx * 2]     = lo;
            ((unsigned int*)emb16)[idx * 2 + 1] = hi;
        }
    }
}

// ---------------------------------------------------------------------------
// PATH A: xp GEMM. 256 WGs = (s,dir,bh,tq). Per WG: 16 t in 2 chunks of 8.
// B (Wih r,z,xn; 48 frags) register-resident; A staged via global_load_lds
// with pre-swizzled source from emb16. Writes xpw bf16 (+ fused biases).
// ---------------------------------------------------------------------------
__global__ __launch_bounds__(512)
void k_xpw(const int* xg, const unsigned short* emb16,
           const unsigned short* Wpwf_u, const unsigned short* Wpwb_u,
           const float* biasWf, const float* biasWb, unsigned short* xpw)
{
    __shared__ unsigned short Abuf[128][256];   // 64 KiB
    const int tid = threadIdx.x, lane = tid & 63, w = tid >> 6;
    const int cid = blockIdx.x;
    const int tq = cid & 3, bh = (cid >> 2) & 1, dir = (cid >> 3) & 1, s = cid >> 4;
    const int t0 = tq * 16;
    const i32x4* Wp = (const i32x4*)(dir ? Wpwb_u : Wpwf_u);
    const float* biasW = dir ? biasWb : biasWf;

    i32x4 B[3][2][8];
#pragma unroll
    for (int g = 0; g < 3; ++g)
#pragma unroll
        for (int q = 0; q < 2; ++q)
#pragma unroll
            for (int kk = 0; kk < 8; ++kk)
                B[g][q][kk] = Wp[((g * 16 + w * 2 + q) * 16 + kk) * 64 + lane];

    float bias_rg[3][2];
#pragma unroll
    for (int g = 0; g < 3; ++g)
#pragma unroll
        for (int q = 0; q < 2; ++q)
            bias_rg[g][q] = biasW[g * 256 + (w * 2 + q) * 16 + (lane & 15)];

    for (int ch = 0; ch < 2; ++ch) {
        __syncthreads();
        // stage 8 t-rows x 16 b x 256 e (bf16) with source pre-swizzle
#pragma unroll
        for (int c = 0; c < 8; ++c) {
            const int trow = 16 * w + 2 * c + (lane >> 5);   // A row 0..127
            const int b = trow & 15;
            const int tok = xg[(s * 32 + bh * 16 + b) * 64 + (t0 + ch * 8 + w)];
            const int kbyte = ((lane & 31) * 16) ^ ((trow & 7) << 4);
            gload16((const char*)emb16 + (size_t)tok * 512 + kbyte,
                    (char*)&Abuf[0][0] + (w * 8 + c) * 1024);
        }
        __syncthreads();

#pragma unroll 1
        for (int tl = 0; tl < 8; ++tl) {
            f32x4 acc[3][2];
#pragma unroll
            for (int g = 0; g < 3; ++g) { acc[g][0] = zero4(); acc[g][1] = zero4(); }
#pragma unroll
            for (int kk = 0; kk < 8; ++kk) {
                const int row = tl * 16 + (lane & 15);
                const int boff = (kk * 64 + (lane >> 4) * 16) ^ ((row & 7) << 4);
                i32x4 a = *(const i32x4*)((const char*)&Abuf[row][0] + boff);
#pragma unroll
                for (int g = 0; g < 3; ++g) {
                    mfma16(acc[g][0], a, B[g][0][kk]);
                    mfma16(acc[g][1], a, B[g][1][kk]);
                }
            }
            const int t = t0 + ch * 8 + tl;
            const int tb = (((s * 2 + dir) * 2 + bh) * 64 + t) * 12288;
#pragma unroll
            for (int g = 0; g < 3; ++g)
#pragma unroll
                for (int q = 0; q < 2; ++q) {
                    const int j = (w * 2 + q) * 16 + (lane & 15);
                    const float bb = bias_rg[g][q];
                    unsigned int lo = (unsigned)f2bf(acc[g][q][0] + bb) |
                                      ((unsigned)f2bf(acc[g][q][1] + bb) << 16);
                    unsigned int hi = (unsigned)f2bf(acc[g][q][2] + bb) |
                                      ((unsigned)f2bf(acc[g][q][3] + bb) << 16);
                    uint2 pk; pk.x = lo; pk.y = hi;
                    *(uint2*)(xpw + tb + (g * 256 + j) * 16 + 4 * (lane >> 4)) = pk;
                }
        }
    }
}

// ---------------------------------------------------------------------------
// PATH A word GRU: 64 WGs (s,dir,bh), 512 thr. Whh (r,z,n) register-resident
// (48 frags/wave). xp staged per step via global_load_lds (24KB dbuf).
// ---------------------------------------------------------------------------
__global__ __launch_bounds__(512)
void k_gru_wordA(const float* stateW,
                 const unsigned short* Wpwf_u, const unsigned short* Wpwb_u,
                 const float* biasWf, const float* biasWb,
                 const unsigned short* xpw, unsigned short* wout)
{
    __shared__ unsigned short Abuf[2][16][256];     // 16 KiB (h)
    __shared__ unsigned short xpL[2][12288];        // 48 KiB (xp bf16)
    const int tid = threadIdx.x, lane = tid & 63, w = tid >> 6;
    const int cid = blockIdx.x;
    const int bh = cid & 1, dir = (cid >> 1) & 1, s = cid >> 2;
    const i32x4* Wp = (const i32x4*)(dir ? Wpwb_u : Wpwf_u);
    const float* biasW = dir ? biasWb : biasWf;
    const int gmap[3] = {0, 1, 3};                  // r, z, hn groups

    i32x4 B[3][2][8];
#pragma unroll
    for (int g = 0; g < 3; ++g)
#pragma unroll
        for (int q = 0; q < 2; ++q)
#pragma unroll
            for (int kk = 0; kk < 8; ++kk)
                B[g][q][kk] = Wp[((gmap[g] * 16 + w * 2 + q) * 16 + 8 + kk) * 64 + lane];

    float bhn[2];
    float hreg[2][4];
#pragma unroll
    for (int q = 0; q < 2; ++q) {
        const int j = (w * 2 + q) * 16 + (lane & 15);
        bhn[q] = biasW[768 + j];
#pragma unroll
        for (int i = 0; i < 4; ++i) {
            const int b = 4 * (lane >> 4) + i;
            float h0 = stateW[dir * 8192 + (bh * 16 + b) * 256 + j];
            hreg[q][i] = h0;
            int byteoff = b * 512 + ((j * 2) ^ ((b & 7) << 4));
            *(unsigned short*)((char*)&Abuf[0][0][0] + byteoff) = f2bf(h0);
        }
    }
    const size_t xbase = (size_t)(((s * 2 + dir) * 2 + bh) * 64) * 24576;  // bytes
    const int tfirst = dir ? 63 : 0;
#pragma unroll
    for (int c = 0; c < 3; ++c)
        gload16((const char*)xpw + xbase + (size_t)tfirst * 24576 +
                    ((w * 3 + c) * 64 + lane) * 16,
                (char*)&xpL[0][0] + (w * 3 + c) * 1024);

    for (int ti = 0; ti < 64; ++ti) {
        __syncthreads();
        const int t = dir ? 63 - ti : ti;
        const int cur = ti & 1, nxt = cur ^ 1;
        if (ti < 63) {
            const int tn = dir ? t - 1 : t + 1;
#pragma unroll
            for (int c = 0; c < 3; ++c)
                gload16((const char*)xpw + xbase + (size_t)tn * 24576 +
                            ((w * 3 + c) * 64 + lane) * 16,
                        (char*)&xpL[nxt][0] + (w * 3 + c) * 1024);
        }
        f32x4 acc[3][2];
#pragma unroll
        for (int g = 0; g < 3; ++g) { acc[g][0] = zero4(); acc[g][1] = zero4(); }
#pragma unroll
        for (int kk = 0; kk < 8; ++kk) {
            const int row = lane & 15;
            const int boff = (kk * 64 + (lane >> 4) * 16) ^ ((row & 7) << 4);
            i32x4 a = *(const i32x4*)((const char*)&Abuf[cur][row][0] + boff);
#pragma unroll
            for (int g = 0; g < 3; ++g) {
                mfma16(acc[g][0], a, B[g][0][kk]);
                mfma16(acc[g][1], a, B[g][1][kk]);
            }
        }
#pragma unroll
        for (int q = 0; q < 2; ++q) {
            const int j = (w * 2 + q) * 16 + (lane & 15);
            uint2 xr = *(const uint2*)((const char*)&xpL[cur][0] +
                        ((0 * 256 + j) * 16 + 4 * (lane >> 4)) * 2);
            uint2 xz = *(const uint2*)((const char*)&xpL[cur][0] +
                        ((1 * 256 + j) * 16 + 4 * (lane >> 4)) * 2);
            uint2 xn = *(const uint2*)((const char*)&xpL[cur][0] +
                        ((2 * 256 + j) * 16 + 4 * (lane >> 4)) * 2);
            float xrf[4] = { bf2f((unsigned short)(xr.x & 0xffffu)),
                             bf2f((unsigned short)(xr.x >> 16)),
                             bf2f((unsigned short)(xr.y & 0xffffu)),
                             bf2f((unsigned short)(xr.y >> 16)) };
            float xzf[4] = { bf2f((unsigned short)(xz.x & 0xffffu)),
                             bf2f((unsigned short)(xz.x >> 16)),
                             bf2f((unsigned short)(xz.y & 0xffffu)),
                             bf2f((unsigned short)(xz.y >> 16)) };
            float xnf[4] = { bf2f((unsigned short)(xn.x & 0xffffu)),
                             bf2f((unsigned short)(xn.x >> 16)),
                             bf2f((unsigned short)(xn.y & 0xffffu)),
                             bf2f((unsigned short)(xn.y >> 16)) };
#pragma unroll
            for (int i = 0; i < 4; ++i) {
                const int b = 4 * (lane >> 4) + i;
                float rv = sigm(xrf[i] + acc[0][q][i]);
                float zv = sigm(xzf[i] + acc[1][q][i]);
                float nv = tanh_(xnf[i] + rv * (acc[2][q][i] + bhn[q]));
                float hnew = (1.f - zv) * nv + zv * hreg[q][i];
                hreg[q][i] = hnew;
                unsigned short hb = f2bf(hnew);
                int byteoff = b * 512 + ((j * 2) ^ ((b & 7) << 4));
                *(unsigned short*)((char*)&Abuf[nxt][0][0] + byteoff) = hb;
                const int r = (s * 64 + t) * 32 + bh * 16 + b;
                const int hcol = dir * 256 + j;
                wout[(((r >> 4) * 16 + (hcol >> 5)) * 64 + (r & 15) +
                      ((hcol >> 3) & 3) * 16) * 8 + (hcol & 7)] = hb;
            }
        }
    }
}

// ---------------------------------------------------------------------------
// PATH B word bi-GRU (R4, streaming): one WG (1024 thr) per (sentence, dir).
// ---------------------------------------------------------------------------
DEVINL void prefetchE(unsigned short (*Ab)[512], const int* xg, const float* embed,
                      int s, int t, int tid)
{
    const int brow = tid >> 5, c = tid & 31;          // 32 rows x 32 thr
    const int tok = xg[(s * 32 + brow) * 64 + t];
    const f32x4* src = (const f32x4*)(embed + (size_t)tok * 256) + c * 2;
    f32x4 f0 = src[0], f1 = src[1];
    i32x4 pk;
    pk.x = (int)((unsigned)f2bf(f0.x) | ((unsigned)f2bf(f0.y) << 16));
    pk.y = (int)((unsigned)f2bf(f0.z) | ((unsigned)f2bf(f0.w) << 16));
    pk.z = (int)((unsigned)f2bf(f1.x) | ((unsigned)f2bf(f1.y) << 16));
    pk.w = (int)((unsigned)f2bf(f1.z) | ((unsigned)f2bf(f1.w) << 16));
    int kbyte = (c * 16) ^ ((brow & 7) << 4);
    *(i32x4*)((char*)&Ab[brow][0] + kbyte) = pk;
}

__global__ __launch_bounds__(1024, 4)
void k_gru_word(const int* xg, const float* embed, const float* stateW,
                const unsigned short* Wpwf_u, const unsigned short* Wpwb_u,
                const float* biasWf, const float* biasWb,
                unsigned short* wout)
{
    __shared__ unsigned short Abuf[2][32][512];   // 64 KiB

    const int tid = threadIdx.x, lane = tid & 63, w = tid >> 6;   // w 0..15
    const int cid = blockIdx.x, s = cid >> 1, dir = cid & 1;
    const i32x4* Wp = (const i32x4*)(dir ? Wpwb_u : Wpwf_u);
    const float* bias = dir ? biasWb : biasWf;

    const int j = w * 16 + (lane & 15);
    float hreg[2][4];
#pragma unroll
    for (int mf = 0; mf < 2; ++mf)
#pragma unroll
        for (int i = 0; i < 4; ++i) {
            int b = mf * 16 + (lane >> 4) * 4 + i;
            float h0 = stateW[dir * 8192 + b * 256 + j];
            hreg[mf][i] = h0;
            int byteoff = ((256 + j) * 2) ^ ((b & 7) << 4);
            *(unsigned short*)((char*)&Abuf[0][b][0] + byteoff) = f2bf(h0);
        }
    const int tfirst = dir ? 63 : 0;
    prefetchE(Abuf[0], xg, embed, s, tfirst, tid);

    const float br = bias[j], bz = bias[256 + j];
    const float bxn = bias[512 + j], bhn = bias[768 + j];

    for (int ti = 0; ti < 64; ++ti) {
        __syncthreads();
        const int t = dir ? 63 - ti : ti;
        const int cur = ti & 1, nxt = cur ^ 1;
        if (ti < 63) prefetchE(Abuf[nxt], xg, embed, s, dir ? t - 1 : t + 1, tid);

        f32x4 acc[4][2];
#pragma unroll
        for (int g = 0; g < 4; ++g) { acc[g][0] = zero4(); acc[g][1] = zero4(); }

        i32x4 bbuf[3][3];
#define LOADB_W(KF, DST)                                                     \
        {                                                                    \
            const int gX = ((KF) < 8) ? 32 : 48;                             \
            DST[0] = Wp[((0 + w)  * 16 + (KF)) * 64 + lane];                 \
            DST[1] = Wp[((16 + w) * 16 + (KF)) * 64 + lane];                 \
            DST[2] = Wp[((gX + w) * 16 + (KF)) * 64 + lane];                 \
        }
        LOADB_W(0, bbuf[0]);
        LOADB_W(1, bbuf[1]);

#pragma unroll
        for (int kf = 0; kf < 16; ++kf) {
            if (kf < 14) LOADB_W(kf + 2, bbuf[(kf + 2) % 3]);
            const int row0 = lane & 15;
            const int boff = (kf * 64 + (lane >> 4) * 16) ^ ((row0 & 7) << 4);
            i32x4 a0 = *(const i32x4*)((const char*)&Abuf[cur][row0][0] + boff);
            i32x4 a1 = *(const i32x4*)((const char*)&Abuf[cur][16 + row0][0] + boff);
            const i32x4* bc = bbuf[kf % 3];
            mfma16(acc[0][0], a0, bc[0]); mfma16(acc[0][1], a1, bc[0]);
            mfma16(acc[1][0], a0, bc[1]); mfma16(acc[1][1], a1, bc[1]);
            if (kf < 8) { mfma16(acc[2][0], a0, bc[2]);
                          mfma16(acc[2][1], a1, bc[2]); }
            else        { mfma16(acc[3][0], a0, bc[2]);
                          mfma16(acc[3][1], a1, bc[2]); }
        }
#undef LOADB_W

#pragma unroll
        for (int mf = 0; mf < 2; ++mf)
#pragma unroll
            for (int i = 0; i < 4; ++i) {
                const int b = mf * 16 + (lane >> 4) * 4 + i;
                float rv = sigm(acc[0][mf][i] + br);
                float zv = sigm(acc[1][mf][i] + bz);
                float nv = tanh_(acc[2][mf][i] + bxn +
                                 rv * (acc[3][mf][i] + bhn));
                float hnew = (1.f - zv) * nv + zv * hreg[mf][i];
                hreg[mf][i] = hnew;
                unsigned short hb = f2bf(hnew);
                int byteoff = ((256 + j) * 2) ^ ((b & 7) << 4);
                *(unsigned short*)((char*)&Abuf[nxt][b][0] + byteoff) = hb;
                int r = (s * 64 + t) * 32 + b;
                int hcol = dir * 256 + j;
                wout[(((r >> 4) * 16 + (hcol >> 5)) * 64 + (r & 15) +
                      ((hcol >> 3) & 3) * 16) * 8 + (hcol & 7)] = hb;
            }
    }
}

// ---------------------------------------------------------------------------
// attention scores v2: A-frags in registers, W staged per-nf into LDS dbuf.
// ---------------------------------------------------------------------------
__global__ __launch_bounds__(512, 4)
void k_attn_score2(const unsigned short* Afrag_u, const unsigned short* Wp_u,
                   const float* wb, const float* wp, float* scores)
{
    __shared__ i32x4 Wl[2][16][64];   // 32 KiB
    const int tid = threadIdx.x, lane = tid & 63, w = tid >> 6;
    const int rblk = blockIdx.x * 8 + w;
    const i32x4* A = (const i32x4*)Afrag_u;
    const i32x4* Wg = (const i32x4*)Wp_u;

    i32x4 a[16];
#pragma unroll
    for (int kf = 0; kf < 16; ++kf) a[kf] = A[(rblk * 16 + kf) * 64 + lane];

    i32x4* wl0 = &Wl[0][0][0];
    i32x4* wl1 = &Wl[1][0][0];
    wl0[tid] = Wg[tid]; wl0[tid + 512] = Wg[tid + 512];

    float partial[4] = {};
    for (int nf = 0; nf < 32; ++nf) {
        __syncthreads();
        if (nf < 31) {
            i32x4* dst = (nf & 1) ? wl0 : wl1;
            dst[tid]       = Wg[(nf + 1) * 1024 + tid];
            dst[tid + 512] = Wg[(nf + 1) * 1024 + tid + 512];
        }
        const i32x4* cur = (nf & 1) ? wl1 : wl0;
        f32x4 acc0 = zero4(), acc1 = zero4();
#pragma unroll
        for (int kf = 0; kf < 16; kf += 2) {
            mfma16(acc0, a[kf],     cur[kf * 64 + lane]);
            mfma16(acc1, a[kf + 1], cur[(kf + 1) * 64 + lane]);
        }
        const int n = nf * 16 + (lane & 15);
        const float wbn = wb[n], wpn = wp[n];
#pragma unroll
        for (int i = 0; i < 4; ++i)
            partial[i] += tanh_(acc0[i] + acc1[i] + wbn) * wpn;
    }
#pragma unroll
    for (int i = 0; i < 4; ++i) {
        float v = partial[i];
        v += __shfl_xor(v, 1); v += __shfl_xor(v, 2);
        v += __shfl_xor(v, 4); v += __shfl_xor(v, 8);
        if ((lane & 15) == 0)
            scores[rblk * 16 + (lane >> 4) * 4 + i] = v;
    }
}

// small-row variant (sentence scores, 512 rows)
__global__ void k_attn_score_small(const unsigned short* Afrag_u,
                                   const unsigned short* Wp_u,
                                   const float* wb, const float* wp, float* scores)
{
    const int tid = threadIdx.x, lane = tid & 63, w = tid >> 6;
    const int rblk = blockIdx.x * 4 + w;
    const i32x4* A = (const i32x4*)Afrag_u;
    const i32x4* Wp = (const i32x4*)Wp_u;
    i32x4 a[16];
#pragma unroll
    for (int kf = 0; kf < 16; ++kf) a[kf] = A[(rblk * 16 + kf) * 64 + lane];

    float partial[4] = {};
    for (int nf = 0; nf < 32; ++nf) {
        f32x4 acc0 = zero4(), acc1 = zero4();
#pragma unroll
        for (int kf = 0; kf < 16; kf += 2) {
            mfma16(acc0, a[kf],     Wp[(nf * 16 + kf) * 64 + lane]);
            mfma16(acc1, a[kf + 1], Wp[(nf * 16 + kf + 1) * 64 + lane]);
        }
        const int n = nf * 16 + (lane & 15);
        const float wbn = wb[n], wpn = wp[n];
#pragma unroll
        for (int i = 0; i < 4; ++i)
            partial[i] += tanh_(acc0[i] + acc1[i] + wbn) * wpn;
    }
#pragma unroll
    for (int i = 0; i < 4; ++i) {
        float v = partial[i];
        v += __shfl_xor(v, 1); v += __shfl_xor(v, 2);
        v += __shfl_xor(v, 4); v += __shfl_xor(v, 8);
        if ((lane & 15) == 0)
            scores[rblk * 16 + (lane >> 4) * 4 + i] = v;
    }
}

// softmax over T + weighted sum -> s (bf16 A-frag layout, rows r2=s*32+b)
__global__ void k_word_pool(const float* scores, const unsigned short* wout,
                            unsigned short* ssFrag)
{
    __shared__ float aL[64];
    const int l = threadIdx.x;                 // 64 threads
    const int bid = blockIdx.x;                // 0..511
    const int s = bid >> 5, b = bid & 31;
    float sc = scores[s * 2048 + l * 32 + b];
    float m = sc;
#pragma unroll
    for (int d = 1; d < 64; d <<= 1) m = fmaxf(m, __shfl_xor(m, d));
    float e = __expf(sc - m), sum = e;
#pragma unroll
    for (int d = 1; d < 64; d <<= 1) sum += __shfl_xor(sum, d);
    aL[l] = e * __builtin_amdgcn_rcpf(sum);
    __syncthreads();

    float acc[8] = {};
    const i32x4* WO = (const i32x4*)wout;
    for (int t = 0; t < 64; ++t) {
        float at = aL[t];
        int cidx = ((s * 128 + t * 2 + (b >> 4)) * 16 + (l >> 2)) * 64 +
                   (b & 15) + (l & 3) * 16;
        i32x4 ch = WO[cidx];
        acc[0] += at * bf2f((unsigned short)((unsigned)ch.x & 0xffffu));
        acc[1] += at * bf2f((unsigned short)((unsigned)ch.x >> 16));
        acc[2] += at * bf2f((unsigned short)((unsigned)ch.y & 0xffffu));
        acc[3] += at * bf2f((unsigned short)((unsigned)ch.y >> 16));
        acc[4] += at * bf2f((unsigned short)((unsigned)ch.z & 0xffffu));
        acc[5] += at * bf2f((unsigned short)((unsigned)ch.z >> 16));
        acc[6] += at * bf2f((unsigned short)((unsigned)ch.w & 0xffffu));
        acc[7] += at * bf2f((unsigned short)((unsigned)ch.w >> 16));
    }
    i32x4 pk;
    pk.x = (int)((unsigned)f2bf(acc[0]) | ((unsigned)f2bf(acc[1]) << 16));
    pk.y = (int)((unsigned)f2bf(acc[2]) | ((unsigned)f2bf(acc[3]) << 16));
    pk.z = (int)((unsigned)f2bf(acc[4]) | ((unsigned)f2bf(acc[5]) << 16));
    pk.w = (int)((unsigned)f2bf(acc[6]) | ((unsigned)f2bf(acc[7]) << 16));
    const int r2 = s * 32 + b;
    int cidx2 = ((r2 >> 4) * 16 + (l >> 2)) * 64 + (r2 & 15) + (l & 3) * 16;
    ((i32x4*)ssFrag)[cidx2] = pk;
}

// xp_sent: s @ sg_Wih_cat^T + bihCat -> [dir][bh][s][3][256][16] f32
__global__ void k_sgih(const unsigned short* ssFrag_u, const unsigned short* Wp_u,
                       const float* bihCat, float* xpSent)
{
    const int tid = threadIdx.x, lane = tid & 63, w = tid >> 6;
    const int rblk = blockIdx.x, ncl = blockIdx.y;
    const i32x4* A = (const i32x4*)ssFrag_u;
    const i32x4* Wp = (const i32x4*)Wp_u;
    i32x4 a[16];
#pragma unroll
    for (int kf = 0; kf < 16; ++kf) a[kf] = A[(rblk * 16 + kf) * 64 + lane];
#pragma unroll
    for (int nfl = 0; nfl < 4; ++nfl) {
        const int nfg = ncl * 16 + w * 4 + nfl;
        f32x4 acc = zero4();
#pragma unroll
        for (int kf = 0; kf < 16; ++kf)
            mfma16(acc, a[kf], Wp[(nfg * 16 + kf) * 64 + lane]);
        const int n = nfg * 16 + (lane & 15);
        const float bb = bihCat[n];
        const int dir = n >= 768, ng = n - dir * 768;
        const int g = ng >> 8, jj = ng & 255;
#pragma unroll
        for (int i = 0; i < 4; ++i) {
            int row = rblk * 16 + (lane >> 4) * 4 + i;
            int s = row >> 5, b = row & 31;
            xpSent[(((dir * 2 + (b >> 4)) * 16 + s) * 12288) +
                   (g * 256 + jj) * 16 + (b & 15)] = acc[i] + bb;
        }
    }
}

// sentence GRU, register-resident Whh: 4 WGs (dir,bh), 512 thr, 16 steps.
__global__ __launch_bounds__(512)
void k_gru_sentA(const float* stateS, const unsigned short* WpF_u,
                 const unsigned short* WpB_u, const float* bhhf, const float* bhhb,
                 const float* xpSent, unsigned short* soFrag)
{
    __shared__ unsigned short Abuf[2][16][256];   // 16 KiB
    __shared__ float xpLs[2][12288];              // 96 KiB
    const int tid = threadIdx.x, lane = tid & 63, w = tid >> 6;
    const int cid = blockIdx.x, bh = cid & 1, dir = cid >> 1;
    const i32x4* Wp = (const i32x4*)(dir ? WpB_u : WpF_u);
    const float* bhh = dir ? bhhb : bhhf;

    i32x4 B[3][2][8];
#pragma unroll
    for (int g = 0; g < 3; ++g)
#pragma unroll
        for (int q = 0; q < 2; ++q)
#pragma unroll
            for (int kk = 0; kk < 8; ++kk)
                B[g][q][kk] = Wp[((g * 16 + w * 2 + q) * 8 + kk) * 64 + lane];

    float bhn[2];
    float hreg[2][4];
#pragma unroll
    for (int q = 0; q < 2; ++q) {
        const int j = (w * 2 + q) * 16 + (lane & 15);
        bhn[q] = bhh[512 + j];
#pragma unroll
        for (int i = 0; i < 4; ++i) {
            const int b = 4 * (lane >> 4) + i;
            float h0 = stateS[dir * 8192 + (bh * 16 + b) * 256 + j];
            hreg[q][i] = h0;
            int byteoff = b * 512 + ((j * 2) ^ ((b & 7) << 4));
            *(unsigned short*)((char*)&Abuf[0][0][0] + byteoff) = f2bf(h0);
        }
    }
    const size_t xbase = (size_t)((dir * 2 + bh) * 16) * 49152;  // bytes
    const int sfirst = dir ? 15 : 0;
#pragma unroll
    for (int c = 0; c < 6; ++c)
        gload16((const char*)xpSent + xbase + (size_t)sfirst * 49152 +
                    ((w * 6 + c) * 64 + lane) * 16,
                (char*)&xpLs[0][0] + (w * 6 + c) * 1024);

    for (int si = 0; si < 16; ++si) {
        __syncthreads();
        const int s = dir ? 15 - si : si;
        const int cur = si & 1, nxt = cur ^ 1;
        if (si < 15) {
            const int sn = dir ? s - 1 : s + 1;
#pragma unroll
            for (int c = 0; c < 6; ++c)
                gload16((const char*)xpSent + xbase + (size_t)sn * 49152 +
                            ((w * 6 + c) * 64 + lane) * 16,
                        (char*)&xpLs[nxt][0] + (w * 6 + c) * 1024);
        }
        f32x4 acc[3][2];
#pragma unroll
        for (int g = 0; g < 3; ++g) { acc[g][0] = zero4(); acc[g][1] = zero4(); }
#pragma unroll
        for (int kk = 0; kk < 8; ++kk) {
            const int row = lane & 15;
            const int boff = (kk * 64 + (lane >> 4) * 16) ^ ((row & 7) << 4);
            i32x4 a = *(const i32x4*)((const char*)&Abuf[cur][row][0] + boff);
#pragma unroll
            for (int g = 0; g < 3; ++g) {
                mfma16(acc[g][0], a, B[g][0][kk]);
                mfma16(acc[g][1], a, B[g][1][kk]);
            }
        }
#pragma unroll
        for (int q = 0; q < 2; ++q) {
            const int j = (w * 2 + q) * 16 + (lane & 15);
            f32x4 xr = *(const f32x4*)((const char*)&xpLs[cur][0] +
                        ((0 * 256 + j) * 16 + 4 * (lane >> 4)) * 4);
            f32x4 xz = *(const f32x4*)((const char*)&xpLs[cur][0] +
                        ((1 * 256 + j) * 16 + 4 * (lane >> 4)) * 4);
            f32x4 xn = *(const f32x4*)((const char*)&xpLs[cur][0] +
                        ((2 * 256 + j) * 16 + 4 * (lane >> 4)) * 4);
#pragma unroll
            for (int i = 0; i < 4; ++i) {
                const int b = 4 * (lane >> 4) + i;
                float rv = sigm(xr[i] + acc[0][q][i]);
                float zv = sigm(xz[i] + acc[1][q][i]);
                float nv = tanh_(xn[i] + rv * (acc[2][q][i] + bhn[q]));
                float hnew = (1.f - zv) * nv + zv * hreg[q][i];
                hreg[q][i] = hnew;
                unsigned short hb = f2bf(hnew);
                int byteoff = b * 512 + ((j * 2) ^ ((b & 7) << 4));
                *(unsigned short*)((char*)&Abuf[nxt][0][0] + byteoff) = hb;
                const int r2 = s * 32 + bh * 16 + b;
                const int hcol = dir * 256 + j;
                soFrag[(((r2 >> 4) * 16 + (hcol >> 5)) * 64 + (r2 & 15) +
                        ((hcol >> 3) & 3) * 16) * 8 + (hcol & 7)] = hb;
            }
        }
    }
}

// sentence softmax over S + pool + final linear (256 thr, k-split matmul)
__global__ void k_sent_pool_fin(const float* scoresS, const unsigned short* soFrag,
                                const float* finW, const float* finb, float* out)
{
    __shared__ float aL[16];
    __shared__ float pooled[512];
    __shared__ float part[4][64];
    const int l = threadIdx.x;   // 0..255
    const int b = blockIdx.x;    // 0..31

    if (l < 64) {
        float sc = (l < 16) ? scoresS[l * 32 + b] : -1e30f;
        float m = sc;
#pragma unroll
        for (int d = 1; d < 16; d <<= 1) m = fmaxf(m, __shfl_xor(m, d));
        float e = (l < 16) ? __expf(sc - m) : 0.f;
        float sum = e;
#pragma unroll
        for (int d = 1; d < 16; d <<= 1) sum += __shfl_xor(sum, d);
        if (l < 16) aL[l] = e * __builtin_amdgcn_rcpf(sum);
    }
    __syncthreads();

    if (l < 64) {
        float acc[8] = {};
        const i32x4* SO = (const i32x4*)soFrag;
        for (int si = 0; si < 16; ++si) {
            float as = aL[si];
            int r2 = si * 32 + b;
            int cidx = ((r2 >> 4) * 16 + (l >> 2)) * 64 + (r2 & 15) + (l & 3) * 16;
            i32x4 ch = SO[cidx];
            acc[0] += as * bf2f((unsigned short)((unsigned)ch.x & 0xffffu));
            acc[1] += as * bf2f((unsigned short)((unsigned)ch.x >> 16));
            acc[2] += as * bf2f((unsigned short)((unsigned)ch.y & 0xffffu));
            acc[3] += as * bf2f((unsigned short)((unsigned)ch.y >> 16));
            acc[4] += as * bf2f((unsigned short)((unsigned)ch.z & 0xffffu));
            acc[5] += as * bf2f((unsigned short)((unsigned)ch.z >> 16));
            acc[6] += as * bf2f((unsigned short)((unsigned)ch.w & 0xffffu));
            acc[7] += as * bf2f((unsigned short)((unsigned)ch.w >> 16));
        }
#pragma unroll
        for (int q = 0; q < 8; ++q) pooled[l * 8 + q] = acc[q];
    }
    __syncthreads();
    {
        const int c = l & 63, kq = l >> 6;
        float v = 0.f;
        if (c < 50) {
            const float* wrow = finW + c * 512 + kq * 128;
            const float* pp = pooled + kq * 128;
            for (int k = 0; k < 128; ++k) v += pp[k] * wrow[k];
        }
        part[kq][c] = v;
    }
    __syncthreads();
    if (l < 50)
        out[b * 50 + l] = finb[l] + part[0][l] + part[1][l] + part[2][l] + part[3][l];
}

// ---------------------------------------------------------------------------
extern "C" void kernel_launch(void* const* d_in, const int* in_sizes, int n_in,
                              void* d_out, int out_size, void* d_ws, size_t ws_size,
                              hipStream_t stream)
{
    if (ws_size < WS_NEED_B) return;
    const int bigA = (ws_size >= WS_NEED_A) ? 1 : 0;

    const int*   x      = (const int*)d_in[0];
    const float* embed  = (const float*)d_in[1];
    const float* wgWihF = (const float*)d_in[2];
    const float* wgWhhF = (const float*)d_in[3];
    const float* wgBihF = (const float*)d_in[4];
    const float* wgBhhF = (const float*)d_in[5];
    const float* wgWihB = (const float*)d_in[6];
    const float* wgWhhB = (const float*)d_in[7];
    const float* wgBihB = (const float*)d_in[8];
    const float* wgBhhB = (const float*)d_in[9];
    const float* wordW  = (const float*)d_in[10];
    const float* wordB  = (const float*)d_in[11];
    const float* wordP  = (const float*)d_in[12];
    const float* sgWihF = (const float*)d_in[13];
    const float* sgWhhF = (const float*)d_in[14];
    const float* sgBihF = (const float*)d_in[15];
    const float* sgBhhF = (const float*)d_in[16];
    const float* sgWihB = (const float*)d_in[17];
    const float* sgWhhB = (const float*)d_in[18];
    const float* sgBihB = (const float*)d_in[19];
    const float* sgBhhB = (const float*)d_in[20];
    const float* sentWm = (const float*)d_in[21];
    const float* sentB  = (const float*)d_in[22];
    const float* sentP  = (const float*)d_in[23];
    const float* finW   = (const float*)d_in[24];
    const float* finB   = (const float*)d_in[25];
    const float* stateW = (const float*)d_in[26];
    const float* stateS = (const float*)d_in[27];

    char* ws = (char*)d_ws;
    unsigned short* Wpwf   = (unsigned short*)(ws + O_WPWF);
    unsigned short* Wpwb   = (unsigned short*)(ws + O_WPWB);
    unsigned short* Wpsgih = (unsigned short*)(ws + O_WPSGIH);
    unsigned short* WpshhF = (unsigned short*)(ws + O_WPSHHF);
    unsigned short* WpshhB = (unsigned short*)(ws + O_WPSHHB);
    unsigned short* WpwW   = (unsigned short*)(ws + O_WPWW);
    unsigned short* WpsW   = (unsigned short*)(ws + O_WPSW);
    float* biasWf  = (float*)(ws + O_BIASWF);
    float* biasWb  = (float*)(ws + O_BIASWB);
    float* bihCat  = (float*)(ws + O_BIHCAT);
    unsigned short* wout   = (unsigned short*)(ws + O_WOUT);
    float* scoresW = (float*)(ws + O_SCORESW);
    unsigned short* ssFrag = (unsigned short*)(ws + O_SSFRAG);
    float* xpSent  = (float*)(ws + O_XPSENT);
    unsigned short* soFrag = (unsigned short*)(ws + O_SOFRAG);
    float* scoresS = (float*)(ws + O_SCORESS);
    unsigned short* emb16  = (unsigned short*)(ws + O_EMB16);
    unsigned short* xpw    = (unsigned short*)(ws + O_XPW);

    k_prep<<<512, 256, 0, stream>>>(wgWihF, wgWhhF, wgWihB, wgWhhB,
                                    sgWihF, sgWihB, sgWhhF, sgWhhB,
                                    wordW, sentWm,
                                    wgBihF, wgBhhF, wgBihB, wgBhhB,
                                    sgBihF, sgBihB, sgBhhF, sgBhhB, embed,
                                    Wpwf, Wpwb, Wpsgih, WpshhF, WpshhB,
                                    WpwW, WpsW, biasWf, biasWb, bihCat,
                                    emb16, bigA);

    if (bigA) {
        k_xpw<<<256, 512, 0, stream>>>(x, emb16, Wpwf, Wpwb, biasWf, biasWb, xpw);
        k_gru_wordA<<<64, 512, 0, stream>>>(stateW, Wpwf, Wpwb, biasWf, biasWb,
                                            xpw, wout);
    } else {
        k_gru_word<<<32, 1024, 0, stream>>>(x, embed, stateW, Wpwf, Wpwb,
                                            biasWf, biasWb, wout);
    }

    k_attn_score2<<<256, 512, 0, stream>>>(wout, WpwW, wordB, wordP, scoresW);
    k_word_pool<<<512, 64, 0, stream>>>(scoresW, wout, ssFrag);

    k_sgih<<<dim3(32, 6), 256, 0, stream>>>(ssFrag, Wpsgih, bihCat, xpSent);
    k_gru_sentA<<<4, 512, 0, stream>>>(stateS, WpshhF, WpshhB, sgBhhF, sgBhhB,
                                       xpSent, soFrag);

    k_attn_score_small<<<8, 256, 0, stream>>>(soFrag, WpsW, sentB, sentP, scoresS);
    k_sent_pool_fin<<<32, 256, 0, stream>>>(scoresS, soFrag, finW, finB,
                                            (float*)d_out);
}

// Round 6
// 445.179 us; speedup vs baseline: 6.8832x; 1.0095x over previous
//
#include <hip/hip_runtime.h>

// ---------------------------------------------------------------------------
// HAN forward on MI355X.
// S=16 sents, B=32 batch, T=64 tokens, E=H=256, 2H=512, NC=50, V=50000.
// R5: swapped-operand GRU/xpw (A=weights rows=hidden, B=activations cols=batch)
// -> vectorized 8B epilogue I/O; xp global->reg (no xp LDS); k_xpw gathers
// embed f32 directly (emb16 pass deleted); word_pool 256thr; attn2 1024thr.
// ---------------------------------------------------------------------------

typedef float  f32x4  __attribute__((ext_vector_type(4)));
typedef int    i32x4  __attribute__((ext_vector_type(4)));
typedef __bf16 bf16x8 __attribute__((ext_vector_type(8)));

#define DEVINL static __device__ __forceinline__

DEVINL unsigned short f2bf(float f) {          // RNE float->bf16
    unsigned int x = __builtin_bit_cast(unsigned int, f);
    x = x + 0x7fffu + ((x >> 16) & 1u);
    return (unsigned short)(x >> 16);
}
DEVINL float bf2f(unsigned short u) {
    unsigned int x = ((unsigned int)u) << 16;
    return __builtin_bit_cast(float, x);
}
DEVINL float bfe16(unsigned int v, int hi) {
    return bf2f((unsigned short)(hi ? (v >> 16) : (v & 0xffffu)));
}
DEVINL float sigm(float x) { return __builtin_amdgcn_rcpf(1.f + __expf(-x)); }
DEVINL float tanh_(float x) {
    x = fminf(fmaxf(x, -20.f), 20.f);
    float e = __expf(-2.f * x);
    return (1.f - e) * __builtin_amdgcn_rcpf(1.f + e);
}
DEVINL void mfma16(f32x4& acc, i32x4 a, i32x4 b) {
    acc = __builtin_amdgcn_mfma_f32_16x16x32_bf16(
        __builtin_bit_cast(bf16x8, a), __builtin_bit_cast(bf16x8, b), acc, 0, 0, 0);
}
DEVINL f32x4 zero4() { f32x4 v = {0.f, 0.f, 0.f, 0.f}; return v; }

// ---- workspace layout (bytes, all 256-aligned) ----------------------------
#define O_WPWF    ((size_t)0)         // word comb fwd  [1024n][512k] bf16 frag
#define O_WPWB    ((size_t)1048576)
#define O_WPSGIH  ((size_t)2097152)   // sent Wih cat   [1536n][512k]
#define O_WPSHHF  ((size_t)3670016)   // sent Whh fwd   [768n][256k]
#define O_WPSHHB  ((size_t)4063232)
#define O_WPWW    ((size_t)4456448)   // word_W^T       [512n][512k]
#define O_WPSW    ((size_t)4980736)   // sent_W^T
#define O_BIASWF  ((size_t)5505024)   // word bias comb [4][256] f32
#define O_BIASWB  ((size_t)5509120)
#define O_BIHCAT  ((size_t)5513216)   // sent bih(+bhh r,z) cat [1536] f32
#define O_WOUT    ((size_t)5519360)   // word_out bf16 A-frag, rows 32768 x 512
#define O_SCORESW ((size_t)39073792)  // word scores f32 [32768]
#define O_SSFRAG  ((size_t)39204864)  // s bf16 A-frag, rows 512 x 512
#define O_XPSENT  ((size_t)39729152)  // xp_sent f32 [dir][bh][s][3][256][16]
#define O_SOFRAG  ((size_t)42874880)  // sent_out bf16 A-frag, rows 512 x 512
#define O_SCORESS ((size_t)43399168)  // sent scores f32 [512]
#define WS_NEED_B ((size_t)43401216)
#define O_XPW     ((size_t)43401216)  // word xp bf16 [chain][t][g][jb][rs][b][4]
#define WS_NEED_A ((size_t)144064512)

// ---------------------------------------------------------------------------
// prep: weight repacks. Fragment-linear layout:
//   short index = ((nf*KF + kf)*64 + lane)*8 + j,
//   n = nf*16 + (lane&15),  k = kf*32 + (lane>>4)*8 + j,  value = B(k, n).
// (Equally valid as A-frag: row = n, k same — used by swapped GEMMs.)
// ---------------------------------------------------------------------------
__global__ void k_prep(const float* wihf, const float* whhf,
                       const float* wihb, const float* whhb,
                       const float* sgihf, const float* sgihb,
                       const float* sghhf, const float* sghhb,
                       const float* wordW, const float* sentW,
                       const float* bihf, const float* bhhf,
                       const float* bihb, const float* bhhb,
                       const float* sgbihf, const float* sgbihb,
                       const float* sgbhhf, const float* sgbhhb,
                       unsigned short* Wpwf, unsigned short* Wpwb,
                       unsigned short* Wpsgih,
                       unsigned short* WpshhF, unsigned short* WpshhB,
                       unsigned short* WpwW, unsigned short* WpsW,
                       float* biasWf, float* biasWb, float* bihCat)
{
    const int tid0 = blockIdx.x * blockDim.x + threadIdx.x;
    const int nth  = gridDim.x * blockDim.x;

    // A) word combined [r|z|xn|hn] x [e(256)|h(256)], both dirs. KF=16.
    for (int idx = tid0; idx < 2 * 524288; idx += nth) {
        int d = idx >> 19, sidx = idx & 524287;
        int j = sidx & 7, chunk = sidx >> 3;
        int lane = chunk & 63, nk = chunk >> 6;
        int kf = nk & 15, nf = nk >> 4;
        int n = nf * 16 + (lane & 15);
        int k = kf * 32 + (lane >> 4) * 8 + j;
        const float* Wih = d ? wihb : wihf;
        const float* Whh = d ? whhb : whhf;
        int g4 = n >> 8, jj = n & 255;
        float v = 0.f;
        if (k < 256) {
            if (g4 == 0) v = Wih[jj * 256 + k];
            else if (g4 == 1) v = Wih[(256 + jj) * 256 + k];
            else if (g4 == 2) v = Wih[(512 + jj) * 256 + k];
        } else {
            int kk = k - 256;
            if (g4 == 0) v = Whh[jj * 256 + kk];
            else if (g4 == 1) v = Whh[(256 + jj) * 256 + kk];
            else if (g4 == 3) v = Whh[(512 + jj) * 256 + kk];
        }
        (d ? Wpwb : Wpwf)[sidx] = f2bf(v);
    }
    // B) sentence Wih cat [1536n][512k]. KF=16.
    for (int idx = tid0; idx < 786432; idx += nth) {
        int j = idx & 7, chunk = idx >> 3;
        int lane = chunk & 63, nk = chunk >> 6;
        int kf = nk & 15, nf = nk >> 4;
        int n = nf * 16 + (lane & 15);
        int k = kf * 32 + (lane >> 4) * 8 + j;
        float v = (n < 768) ? sgihf[n * 512 + k] : sgihb[(n - 768) * 512 + k];
        Wpsgih[idx] = f2bf(v);
    }
    // C) sentence Whh f/b [768n][256k]. KF=8.
    for (int idx = tid0; idx < 2 * 196608; idx += nth) {
        int d = idx >= 196608;
        int sidx = d ? idx - 196608 : idx;
        int j = sidx & 7, chunk = sidx >> 3;
        int lane = chunk & 63, nk = chunk >> 6;
        int kf = nk & 7, nf = nk >> 3;
        int n = nf * 16 + (lane & 15);
        int k = kf * 32 + (lane >> 4) * 8 + j;
        float v = (d ? sghhb : sghhf)[n * 256 + k];
        (d ? WpshhB : WpshhF)[sidx] = f2bf(v);
    }
    // D) word_W / sent_W transposed: B(k,n) = W[k*512+n]. KF=16.
    for (int idx = tid0; idx < 2 * 262144; idx += nth) {
        int d = idx >> 18, sidx = idx & 262143;
        int j = sidx & 7, chunk = sidx >> 3;
        int lane = chunk & 63, nk = chunk >> 6;
        int kf = nk & 15, nf = nk >> 4;
        int n = nf * 16 + (lane & 15);
        int k = kf * 32 + (lane >> 4) * 8 + j;
        float v = (d ? sentW : wordW)[k * 512 + n];
        (d ? WpsW : WpwW)[sidx] = f2bf(v);
    }
    // E) word bias comb: [r: bih+bhh][z: bih+bhh][xn: bih][hn: bhh]
    for (int idx = tid0; idx < 2048; idx += nth) {
        int d = idx >> 10, i = idx & 1023;
        int g4 = i >> 8, j = i & 255;
        const float* bi = d ? bihb : bihf;
        const float* bh = d ? bhhb : bhhf;
        float v = (g4 == 0) ? bi[j] + bh[j]
                : (g4 == 1) ? bi[256 + j] + bh[256 + j]
                : (g4 == 2) ? bi[512 + j] : bh[512 + j];
        (d ? biasWb : biasWf)[i] = v;
    }
    // F) sentence bih cat (+bhh folded for r,z; n keeps bih only)
    for (int idx = tid0; idx < 1536; idx += nth) {
        int d = idx >= 768, j = d ? idx - 768 : idx;
        const float* bi = d ? sgbihb : sgbihf;
        const float* bh = d ? sgbhhb : sgbhhf;
        bihCat[idx] = bi[j] + ((j < 512) ? bh[j] : 0.f);
    }
}

// ---------------------------------------------------------------------------
// PATH A xp GEMM (swapped): A = Wih (rows j, gates r/z/xn), B = e^T (cols b).
// WG = (s,dir,bh,tq): 16 t sequential, e reg-staged f32->bf16 into swizzled
// LDS. Writes xpw bf16 (+ folded r/z/xn biases), wave-coalesced layout:
//   byte = chain*1572864 + t*24576 + g*8192 + jb*512 + rsub*128 + b*8.
// ---------------------------------------------------------------------------
__global__ __launch_bounds__(512, 2)
void k_xpw(const int* xg, const float* embed,
           const unsigned short* Wpwf_u, const unsigned short* Wpwb_u,
           const float* biasWf, const float* biasWb, unsigned short* xpw)
{
    __shared__ unsigned short Ebuf[2][16][256];   // 16 KiB, swizzled
    const int tid = threadIdx.x, lane = tid & 63, w = tid >> 6;
    const int cid = blockIdx.x;
    const int tq = cid & 3, bh = (cid >> 2) & 1, dir = (cid >> 3) & 1, s = cid >> 4;
    const int t0 = tq * 16;
    const i32x4* Wp = (const i32x4*)(dir ? Wpwb_u : Wpwf_u);
    const float* biasW = dir ? biasWb : biasWf;
    const int b = lane & 15, rsub = lane >> 4;

    i32x4 A[3][2][8];
#pragma unroll
    for (int g = 0; g < 3; ++g)
#pragma unroll
        for (int q = 0; q < 2; ++q)
#pragma unroll
            for (int kk = 0; kk < 8; ++kk)
                A[g][q][kk] = Wp[((g * 16 + w * 2 + q) * 16 + kk) * 64 + lane];

    unsigned int biasp[3][2][2];
#pragma unroll
    for (int g = 0; g < 3; ++g)
#pragma unroll
        for (int q = 0; q < 2; ++q) {
            const int j0 = g * 256 + (w * 2 + q) * 16 + rsub * 4;
            biasp[g][q][0] = (unsigned)f2bf(biasW[j0]) |
                             ((unsigned)f2bf(biasW[j0 + 1]) << 16);
            biasp[g][q][1] = (unsigned)f2bf(biasW[j0 + 2]) |
                             ((unsigned)f2bf(biasW[j0 + 3]) << 16);
        }

    const int sb = tid >> 5, sc = tid & 31;      // staging: b-row, e-chunk
    const int tokrow = (s * 32 + bh * 16 + sb) * 64;
    const int sdst = sb * 512 + ((sc * 16) ^ ((sb & 7) << 4));

#define STAGE_E(BUF, T)                                                       \
    {                                                                         \
        const int tok = xg[tokrow + (T)];                                     \
        const f32x4* src = (const f32x4*)(embed + (size_t)tok * 256 + sc * 8);\
        f32x4 e0 = src[0], e1 = src[1];                                       \
        i32x4 pk;                                                             \
        pk.x = (int)((unsigned)f2bf(e0.x) | ((unsigned)f2bf(e0.y) << 16));    \
        pk.y = (int)((unsigned)f2bf(e0.z) | ((unsigned)f2bf(e0.w) << 16));    \
        pk.z = (int)((unsigned)f2bf(e1.x) | ((unsigned)f2bf(e1.y) << 16));    \
        pk.w = (int)((unsigned)f2bf(e1.z) | ((unsigned)f2bf(e1.w) << 16));    \
        *(i32x4*)((char*)&Ebuf[BUF][0][0] + sdst) = pk;                       \
    }

    STAGE_E(0, t0);
    const size_t chain = (size_t)((s * 2 + dir) * 2 + bh);
    char* const xpBase = (char*)xpw + chain * 1572864 +
                         (size_t)(rsub * 128 + b * 8);

    for (int tl = 0; tl < 16; ++tl) {
        __syncthreads();
        const int t = t0 + tl, cur = tl & 1, nxt = cur ^ 1;
        if (tl < 15) STAGE_E(nxt, t + 1);

        f32x4 acc[3][2];
#pragma unroll
        for (int g = 0; g < 3; ++g) { acc[g][0] = zero4(); acc[g][1] = zero4(); }
#pragma unroll
        for (int kk = 0; kk < 8; ++kk) {
            const int roff = b * 512 + ((kk * 64 + rsub * 16) ^ ((b & 7) << 4));
            i32x4 eb = *(const i32x4*)((const char*)&Ebuf[cur][0][0] + roff);
            mfma16(acc[0][0], A[0][0][kk], eb); mfma16(acc[0][1], A[0][1][kk], eb);
            mfma16(acc[1][0], A[1][0][kk], eb); mfma16(acc[1][1], A[1][1][kk], eb);
            mfma16(acc[2][0], A[2][0][kk], eb); mfma16(acc[2][1], A[2][1][kk], eb);
        }
        char* ob = xpBase + (size_t)t * 24576;
#pragma unroll
        for (int g = 0; g < 3; ++g)
#pragma unroll
            for (int q = 0; q < 2; ++q) {
                unsigned short us[4];
#pragma unroll
                for (int i = 0; i < 4; ++i)
                    us[i] = f2bf(acc[g][q][i] + bfe16(biasp[g][q][i >> 1], i & 1));
                uint2 pk;
                pk.x = (unsigned)us[0] | ((unsigned)us[1] << 16);
                pk.y = (unsigned)us[2] | ((unsigned)us[3] << 16);
                *(uint2*)(ob + g * 8192 + (w * 2 + q) * 512) = pk;
            }
    }
#undef STAGE_E
}

// ---------------------------------------------------------------------------
// PATH A word GRU (swapped): A = Whh (r,z,hn; register-resident, 48 frags),
// B = h^T in swizzled LDS dbuf (16 KiB total). xp read global->reg (8B,
// wave-coalesced). Epilogue: 4 consecutive j per thread -> 8B LDS + 8B wout.
// ---------------------------------------------------------------------------
__global__ __launch_bounds__(512, 2)
void k_gru_wordA(const float* stateW,
                 const unsigned short* Wpwf_u, const unsigned short* Wpwb_u,
                 const float* biasWf, const float* biasWb,
                 const unsigned short* xpw, unsigned short* wout)
{
    __shared__ unsigned short Hbuf[2][16][256];   // 16 KiB
    const int tid = threadIdx.x, lane = tid & 63, w = tid >> 6;
    const int cid = blockIdx.x, bh = cid & 1, dir = (cid >> 1) & 1, s = cid >> 2;
    const i32x4* Wp = (const i32x4*)(dir ? Wpwb_u : Wpwf_u);
    const float* biasW = dir ? biasWb : biasWf;
    const int b = lane & 15, rsub = lane >> 4;
    const int gmap[3] = {0, 1, 3};                // r, z, hn

    i32x4 A[3][2][8];
#pragma unroll
    for (int g = 0; g < 3; ++g)
#pragma unroll
        for (int q = 0; q < 2; ++q)
#pragma unroll
            for (int kk = 0; kk < 8; ++kk)
                A[g][q][kk] =
                    Wp[((gmap[g] * 16 + w * 2 + q) * 16 + 8 + kk) * 64 + lane];

    unsigned int bhnp[2][2];
    float hreg[2][4];
#pragma unroll
    for (int q = 0; q < 2; ++q) {
        const int j0 = (w * 2 + q) * 16 + rsub * 4;
        f32x4 h0 = *(const f32x4*)(stateW + dir * 8192 + (bh * 16 + b) * 256 + j0);
        bhnp[q][0] = (unsigned)f2bf(biasW[768 + j0]) |
                     ((unsigned)f2bf(biasW[768 + j0 + 1]) << 16);
        bhnp[q][1] = (unsigned)f2bf(biasW[768 + j0 + 2]) |
                     ((unsigned)f2bf(biasW[768 + j0 + 3]) << 16);
        hreg[q][0] = h0.x; hreg[q][1] = h0.y; hreg[q][2] = h0.z; hreg[q][3] = h0.w;
        uint2 pk;
        pk.x = (unsigned)f2bf(h0.x) | ((unsigned)f2bf(h0.y) << 16);
        pk.y = (unsigned)f2bf(h0.z) | ((unsigned)f2bf(h0.w) << 16);
        const int boff = b * 512 + (((w * 2 + q) * 32 + rsub * 8) ^ ((b & 7) << 4));
        *(uint2*)((char*)&Hbuf[0][0][0] + boff) = pk;
    }
    const size_t chain = (size_t)((s * 2 + dir) * 2 + bh);
    const char* const xpBase = (const char*)xpw + chain * 1572864 +
                               (size_t)(rsub * 128 + b * 8);

    for (int ti = 0; ti < 64; ++ti) {
        __syncthreads();
        const int t = dir ? 63 - ti : ti;
        const int cur = ti & 1, nxt = cur ^ 1;

        uint2 xpv[3][2];
        const char* xb = xpBase + (size_t)t * 24576;
#pragma unroll
        for (int g = 0; g < 3; ++g)
#pragma unroll
            for (int q = 0; q < 2; ++q)
                xpv[g][q] = *(const uint2*)(xb + g * 8192 + (w * 2 + q) * 512);

        f32x4 acc[3][2];
#pragma unroll
        for (int g = 0; g < 3; ++g) { acc[g][0] = zero4(); acc[g][1] = zero4(); }
#pragma unroll
        for (int kk = 0; kk < 8; ++kk) {
            const int roff = b * 512 + ((kk * 64 + rsub * 16) ^ ((b & 7) << 4));
            i32x4 hb = *(const i32x4*)((const char*)&Hbuf[cur][0][0] + roff);
            mfma16(acc[0][0], A[0][0][kk], hb); mfma16(acc[0][1], A[0][1][kk], hb);
            mfma16(acc[1][0], A[1][0][kk], hb); mfma16(acc[1][1], A[1][1][kk], hb);
            mfma16(acc[2][0], A[2][0][kk], hb); mfma16(acc[2][1], A[2][1][kk], hb);
        }
        const int r = (s * 64 + t) * 32 + bh * 16 + b;
#pragma unroll
        for (int q = 0; q < 2; ++q) {
            unsigned short us[4];
#pragma unroll
            for (int i = 0; i < 4; ++i) {
                const unsigned xr = (i < 2) ? xpv[0][q].x : xpv[0][q].y;
                const unsigned xz = (i < 2) ? xpv[1][q].x : xpv[1][q].y;
                const unsigned xn = (i < 2) ? xpv[2][q].x : xpv[2][q].y;
                float rv = sigm(bfe16(xr, i & 1) + acc[0][q][i]);
                float zv = sigm(bfe16(xz, i & 1) + acc[1][q][i]);
                float nv = tanh_(bfe16(xn, i & 1) +
                                 rv * (acc[2][q][i] + bfe16(bhnp[q][i >> 1], i & 1)));
                float h = (1.f - zv) * nv + zv * hreg[q][i];
                hreg[q][i] = h;
                us[i] = f2bf(h);
            }
            uint2 pk;
            pk.x = (unsigned)us[0] | ((unsigned)us[1] << 16);
            pk.y = (unsigned)us[2] | ((unsigned)us[3] << 16);
            const int boff = b * 512 + (((w * 2 + q) * 32 + rsub * 8) ^ ((b & 7) << 4));
            *(uint2*)((char*)&Hbuf[nxt][0][0] + boff) = pk;
            const int hcol = dir * 256 + (w * 2 + q) * 16 + rsub * 4;
            const int widx = (((r >> 4) * 16 + (hcol >> 5)) * 64 + (r & 15) +
                              ((hcol >> 3) & 3) * 16) * 8 + (hcol & 7);
            *(uint2*)(wout + widx) = pk;
        }
    }
}

// ---------------------------------------------------------------------------
// PATH B word bi-GRU (R4 streaming fallback): 1 WG (1024 thr) / (sent, dir).
// ---------------------------------------------------------------------------
DEVINL void prefetchE(unsigned short (*Ab)[512], const int* xg, const float* embed,
                      int s, int t, int tid)
{
    const int brow = tid >> 5, c = tid & 31;
    const int tok = xg[(s * 32 + brow) * 64 + t];
    const f32x4* src = (const f32x4*)(embed + (size_t)tok * 256) + c * 2;
    f32x4 f0 = src[0], f1 = src[1];
    i32x4 pk;
    pk.x = (int)((unsigned)f2bf(f0.x) | ((unsigned)f2bf(f0.y) << 16));
    pk.y = (int)((unsigned)f2bf(f0.z) | ((unsigned)f2bf(f0.w) << 16));
    pk.z = (int)((unsigned)f2bf(f1.x) | ((unsigned)f2bf(f1.y) << 16));
    pk.w = (int)((unsigned)f2bf(f1.z) | ((unsigned)f2bf(f1.w) << 16));
    int kbyte = (c * 16) ^ ((brow & 7) << 4);
    *(i32x4*)((char*)&Ab[brow][0] + kbyte) = pk;
}

__global__ __launch_bounds__(1024, 4)
void k_gru_word(const int* xg, const float* embed, const float* stateW,
                const unsigned short* Wpwf_u, const unsigned short* Wpwb_u,
                const float* biasWf, const float* biasWb,
                unsigned short* wout)
{
    __shared__ unsigned short Abuf[2][32][512];
    const int tid = threadIdx.x, lane = tid & 63, w = tid >> 6;
    const int cid = blockIdx.x, s = cid >> 1, dir = cid & 1;
    const i32x4* Wp = (const i32x4*)(dir ? Wpwb_u : Wpwf_u);
    const float* bias = dir ? biasWb : biasWf;

    const int j = w * 16 + (lane & 15);
    float hreg[2][4];
#pragma unroll
    for (int mf = 0; mf < 2; ++mf)
#pragma unroll
        for (int i = 0; i < 4; ++i) {
            int b = mf * 16 + (lane >> 4) * 4 + i;
            float h0 = stateW[dir * 8192 + b * 256 + j];
            hreg[mf][i] = h0;
            int byteoff = ((256 + j) * 2) ^ ((b & 7) << 4);
            *(unsigned short*)((char*)&Abuf[0][b][0] + byteoff) = f2bf(h0);
        }
    const int tfirst = dir ? 63 : 0;
    prefetchE(Abuf[0], xg, embed, s, tfirst, tid);

    const float br = bias[j], bz = bias[256 + j];
    const float bxn = bias[512 + j], bhn = bias[768 + j];

    for (int ti = 0; ti < 64; ++ti) {
        __syncthreads();
        const int t = dir ? 63 - ti : ti;
        const int cur = ti & 1, nxt = cur ^ 1;
        if (ti < 63) prefetchE(Abuf[nxt], xg, embed, s, dir ? t - 1 : t + 1, tid);

        f32x4 acc[4][2];
#pragma unroll
        for (int g = 0; g < 4; ++g) { acc[g][0] = zero4(); acc[g][1] = zero4(); }

        i32x4 bbuf[3][3];
#define LOADB_W(KF, DST)                                                     \
        {                                                                    \
            const int gX = ((KF) < 8) ? 32 : 48;                             \
            DST[0] = Wp[((0 + w)  * 16 + (KF)) * 64 + lane];                 \
            DST[1] = Wp[((16 + w) * 16 + (KF)) * 64 + lane];                 \
            DST[2] = Wp[((gX + w) * 16 + (KF)) * 64 + lane];                 \
        }
        LOADB_W(0, bbuf[0]);
        LOADB_W(1, bbuf[1]);
#pragma unroll
        for (int kf = 0; kf < 16; ++kf) {
            if (kf < 14) LOADB_W(kf + 2, bbuf[(kf + 2) % 3]);
            const int row0 = lane & 15;
            const int boff = (kf * 64 + (lane >> 4) * 16) ^ ((row0 & 7) << 4);
            i32x4 a0 = *(const i32x4*)((const char*)&Abuf[cur][row0][0] + boff);
            i32x4 a1 = *(const i32x4*)((const char*)&Abuf[cur][16 + row0][0] + boff);
            const i32x4* bc = bbuf[kf % 3];
            mfma16(acc[0][0], a0, bc[0]); mfma16(acc[0][1], a1, bc[0]);
            mfma16(acc[1][0], a0, bc[1]); mfma16(acc[1][1], a1, bc[1]);
            if (kf < 8) { mfma16(acc[2][0], a0, bc[2]);
                          mfma16(acc[2][1], a1, bc[2]); }
            else        { mfma16(acc[3][0], a0, bc[2]);
                          mfma16(acc[3][1], a1, bc[2]); }
        }
#undef LOADB_W
#pragma unroll
        for (int mf = 0; mf < 2; ++mf)
#pragma unroll
            for (int i = 0; i < 4; ++i) {
                const int b = mf * 16 + (lane >> 4) * 4 + i;
                float rv = sigm(acc[0][mf][i] + br);
                float zv = sigm(acc[1][mf][i] + bz);
                float nv = tanh_(acc[2][mf][i] + bxn + rv * (acc[3][mf][i] + bhn));
                float hnew = (1.f - zv) * nv + zv * hreg[mf][i];
                hreg[mf][i] = hnew;
                unsigned short hb = f2bf(hnew);
                int byteoff = ((256 + j) * 2) ^ ((b & 7) << 4);
                *(unsigned short*)((char*)&Abuf[nxt][b][0] + byteoff) = hb;
                int r = (s * 64 + t) * 32 + b;
                int hcol = dir * 256 + j;
                wout[(((r >> 4) * 16 + (hcol >> 5)) * 64 + (r & 15) +
                      ((hcol >> 3) & 3) * 16) * 8 + (hcol & 7)] = hb;
            }
    }
}

// ---------------------------------------------------------------------------
// attention scores: A-frags in registers (read once), W staged into LDS dbuf.
// 1024 thr, 16 rblk/WG -> W re-streamed only 128x (was 256x).
// ---------------------------------------------------------------------------
__global__ __launch_bounds__(1024, 4)
void k_attn_score2(const unsigned short* Afrag_u, const unsigned short* Wp_u,
                   const float* wb, const float* wp, float* scores)
{
    __shared__ i32x4 Wl[2][16][64];   // 32 KiB
    const int tid = threadIdx.x, lane = tid & 63, w = tid >> 6;
    const int rblk = blockIdx.x * 16 + w;
    const i32x4* A = (const i32x4*)Afrag_u;
    const i32x4* Wg = (const i32x4*)Wp_u;

    i32x4 a[16];
#pragma unroll
    for (int kf = 0; kf < 16; ++kf) a[kf] = A[(rblk * 16 + kf) * 64 + lane];

    i32x4* wl0 = &Wl[0][0][0];
    i32x4* wl1 = &Wl[1][0][0];
    wl0[tid] = Wg[tid];

    float partial[4] = {};
    for (int nf = 0; nf < 32; ++nf) {
        __syncthreads();
        if (nf < 31) {
            i32x4* dst = (nf & 1) ? wl0 : wl1;
            dst[tid] = Wg[(nf + 1) * 1024 + tid];
        }
        const i32x4* cur = (nf & 1) ? wl1 : wl0;
        f32x4 acc0 = zero4(), acc1 = zero4();
#pragma unroll
        for (int kf = 0; kf < 16; kf += 2) {
            mfma16(acc0, a[kf],     cur[kf * 64 + lane]);
            mfma16(acc1, a[kf + 1], cur[(kf + 1) * 64 + lane]);
        }
        const int n = nf * 16 + (lane & 15);
        const float wbn = wb[n], wpn = wp[n];
#pragma unroll
        for (int i = 0; i < 4; ++i)
            partial[i] += tanh_(acc0[i] + acc1[i] + wbn) * wpn;
    }
#pragma unroll
    for (int i = 0; i < 4; ++i) {
        float v = partial[i];
        v += __shfl_xor(v, 1); v += __shfl_xor(v, 2);
        v += __shfl_xor(v, 4); v += __shfl_xor(v, 8);
        if ((lane & 15) == 0)
            scores[rblk * 16 + (lane >> 4) * 4 + i] = v;
    }
}

// small-row variant (sentence scores, 512 rows)
__global__ void k_attn_score_small(const unsigned short* Afrag_u,
                                   const unsigned short* Wp_u,
                                   const float* wb, const float* wp, float* scores)
{
    const int tid = threadIdx.x, lane = tid & 63, w = tid >> 6;
    const int rblk = blockIdx.x * 4 + w;
    const i32x4* A = (const i32x4*)Afrag_u;
    const i32x4* Wp = (const i32x4*)Wp_u;
    i32x4 a[16];
#pragma unroll
    for (int kf = 0; kf < 16; ++kf) a[kf] = A[(rblk * 16 + kf) * 64 + lane];

    float partial[4] = {};
    for (int nf = 0; nf < 32; ++nf) {
        f32x4 acc0 = zero4(), acc1 = zero4();
#pragma unroll
        for (int kf = 0; kf < 16; kf += 2) {
            mfma16(acc0, a[kf],     Wp[(nf * 16 + kf) * 64 + lane]);
            mfma16(acc1, a[kf + 1], Wp[(nf * 16 + kf + 1) * 64 + lane]);
        }
        const int n = nf * 16 + (lane & 15);
        const float wbn = wb[n], wpn = wp[n];
#pragma unroll
        for (int i = 0; i < 4; ++i)
            partial[i] += tanh_(acc0[i] + acc1[i] + wbn) * wpn;
    }
#pragma unroll
    for (int i = 0; i < 4; ++i) {
        float v = partial[i];
        v += __shfl_xor(v, 1); v += __shfl_xor(v, 2);
        v += __shfl_xor(v, 4); v += __shfl_xor(v, 8);
        if ((lane & 15) == 0)
            scores[rblk * 16 + (lane >> 4) * 4 + i] = v;
    }
}

// softmax over T + weighted sum -> s (bf16 A-frag layout). 256 thr: 4 waves
// split the t-loop, LDS tree-reduce.
__global__ void k_word_pool(const float* scores, const unsigned short* wout,
                            unsigned short* ssFrag)
{
    __shared__ float aL[64];
    __shared__ float part[4][64][8];
    const int tid = threadIdx.x, l = tid & 63, w = tid >> 6;
    const int bid = blockIdx.x;                // 0..511
    const int s = bid >> 5, b = bid & 31;
    if (w == 0) {
        float sc = scores[s * 2048 + l * 32 + b];
        float m = sc;
#pragma unroll
        for (int d = 1; d < 64; d <<= 1) m = fmaxf(m, __shfl_xor(m, d));
        float e = __expf(sc - m), sum = e;
#pragma unroll
        for (int d = 1; d < 64; d <<= 1) sum += __shfl_xor(sum, d);
        aL[l] = e * __builtin_amdgcn_rcpf(sum);
    }
    __syncthreads();

    float acc[8] = {};
    const i32x4* WO = (const i32x4*)wout;
    for (int tt = 0; tt < 16; ++tt) {
        const int t = w * 16 + tt;
        float at = aL[t];
        int cidx = ((s * 128 + t * 2 + (b >> 4)) * 16 + (l >> 2)) * 64 +
                   (b & 15) + (l & 3) * 16;
        i32x4 ch = WO[cidx];
        acc[0] += at * bf2f((unsigned short)((unsigned)ch.x & 0xffffu));
        acc[1] += at * bf2f((unsigned short)((unsigned)ch.x >> 16));
        acc[2] += at * bf2f((unsigned short)((unsigned)ch.y & 0xffffu));
        acc[3] += at * bf2f((unsigned short)((unsigned)ch.y >> 16));
        acc[4] += at * bf2f((unsigned short)((unsigned)ch.z & 0xffffu));
        acc[5] += at * bf2f((unsigned short)((unsigned)ch.z >> 16));
        acc[6] += at * bf2f((unsigned short)((unsigned)ch.w & 0xffffu));
        acc[7] += at * bf2f((unsigned short)((unsigned)ch.w >> 16));
    }
#pragma unroll
    for (int q = 0; q < 8; ++q) part[w][l][q] = acc[q];
    __syncthreads();
    if (w == 0) {
        float fin[8];
#pragma unroll
        for (int q = 0; q < 8; ++q)
            fin[q] = part[0][l][q] + part[1][l][q] + part[2][l][q] + part[3][l][q];
        i32x4 pk;
        pk.x = (int)((unsigned)f2bf(fin[0]) | ((unsigned)f2bf(fin[1]) << 16));
        pk.y = (int)((unsigned)f2bf(fin[2]) | ((unsigned)f2bf(fin[3]) << 16));
        pk.z = (int)((unsigned)f2bf(fin[4]) | ((unsigned)f2bf(fin[5]) << 16));
        pk.w = (int)((unsigned)f2bf(fin[6]) | ((unsigned)f2bf(fin[7]) << 16));
        const int r2 = s * 32 + b;
        int cidx2 = ((r2 >> 4) * 16 + (l >> 2)) * 64 + (r2 & 15) + (l & 3) * 16;
        ((i32x4*)ssFrag)[cidx2] = pk;
    }
}

// xp_sent: s @ sg_Wih_cat^T + bihCat -> [dir][bh][s][3][256][16] f32
__global__ void k_sgih(const unsigned short* ssFrag_u, const unsigned short* Wp_u,
                       const float* bihCat, float* xpSent)
{
    const int tid = threadIdx.x, lane = tid & 63, w = tid >> 6;
    const int rblk = blockIdx.x, ncl = blockIdx.y;
    const i32x4* A = (const i32x4*)ssFrag_u;
    const i32x4* Wp = (const i32x4*)Wp_u;
    i32x4 a[16];
#pragma unroll
    for (int kf = 0; kf < 16; ++kf) a[kf] = A[(rblk * 16 + kf) * 64 + lane];
#pragma unroll
    for (int nfl = 0; nfl < 4; ++nfl) {
        const int nfg = ncl * 16 + w * 4 + nfl;
        f32x4 acc = zero4();
#pragma unroll
        for (int kf = 0; kf < 16; ++kf)
            mfma16(acc, a[kf], Wp[(nfg * 16 + kf) * 64 + lane]);
        const int n = nfg * 16 + (lane & 15);
        const float bb = bihCat[n];
        const int dir = n >= 768, ng = n - dir * 768;
        const int g = ng >> 8, jj = ng & 255;
#pragma unroll
        for (int i = 0; i < 4; ++i) {
            int row = rblk * 16 + (lane >> 4) * 4 + i;
            int s = row >> 5, b = row & 31;
            xpSent[(((dir * 2 + (b >> 4)) * 16 + s) * 12288) +
                   (g * 256 + jj) * 16 + (b & 15)] = acc[i] + bb;
        }
    }
}

DEVINL void gload16(const void* gsrc, void* ldst) {
    __builtin_amdgcn_global_load_lds(
        (const __attribute__((address_space(1))) unsigned int*)gsrc,
        (__attribute__((address_space(3))) unsigned int*)ldst, 16, 0, 0);
}

// sentence GRU, register-resident Whh: 4 WGs (dir,bh), 512 thr, 16 steps.
__global__ __launch_bounds__(512)
void k_gru_sentA(const float* stateS, const unsigned short* WpF_u,
                 const unsigned short* WpB_u, const float* bhhf, const float* bhhb,
                 const float* xpSent, unsigned short* soFrag)
{
    __shared__ unsigned short Abuf[2][16][256];   // 16 KiB
    __shared__ float xpLs[2][12288];              // 96 KiB
    const int tid = threadIdx.x, lane = tid & 63, w = tid >> 6;
    const int cid = blockIdx.x, bh = cid & 1, dir = cid >> 1;
    const i32x4* Wp = (const i32x4*)(dir ? WpB_u : WpF_u);
    const float* bhh = dir ? bhhb : bhhf;

    i32x4 B[3][2][8];
#pragma unroll
    for (int g = 0; g < 3; ++g)
#pragma unroll
        for (int q = 0; q < 2; ++q)
#pragma unroll
            for (int kk = 0; kk < 8; ++kk)
                B[g][q][kk] = Wp[((g * 16 + w * 2 + q) * 8 + kk) * 64 + lane];

    float bhn[2];
    float hreg[2][4];
#pragma unroll
    for (int q = 0; q < 2; ++q) {
        const int j = (w * 2 + q) * 16 + (lane & 15);
        bhn[q] = bhh[512 + j];
#pragma unroll
        for (int i = 0; i < 4; ++i) {
            const int b = 4 * (lane >> 4) + i;
            float h0 = stateS[dir * 8192 + (bh * 16 + b) * 256 + j];
            hreg[q][i] = h0;
            int byteoff = b * 512 + ((j * 2) ^ ((b & 7) << 4));
            *(unsigned short*)((char*)&Abuf[0][0][0] + byteoff) = f2bf(h0);
        }
    }
    const size_t xbase = (size_t)((dir * 2 + bh) * 16) * 49152;
    const int sfirst = dir ? 15 : 0;
#pragma unroll
    for (int c = 0; c < 6; ++c)
        gload16((const char*)xpSent + xbase + (size_t)sfirst * 49152 +
                    ((w * 6 + c) * 64 + lane) * 16,
                (char*)&xpLs[0][0] + (w * 6 + c) * 1024);

    for (int si = 0; si < 16; ++si) {
        __syncthreads();
        const int s = dir ? 15 - si : si;
        const int cur = si & 1, nxt = cur ^ 1;
        if (si < 15) {
            const int sn = dir ? s - 1 : s + 1;
#pragma unroll
            for (int c = 0; c < 6; ++c)
                gload16((const char*)xpSent + xbase + (size_t)sn * 49152 +
                            ((w * 6 + c) * 64 + lane) * 16,
                        (char*)&xpLs[nxt][0] + (w * 6 + c) * 1024);
        }
        f32x4 acc[3][2];
#pragma unroll
        for (int g = 0; g < 3; ++g) { acc[g][0] = zero4(); acc[g][1] = zero4(); }
#pragma unroll
        for (int kk = 0; kk < 8; ++kk) {
            const int row = lane & 15;
            const int boff = (kk * 64 + (lane >> 4) * 16) ^ ((row & 7) << 4);
            i32x4 a = *(const i32x4*)((const char*)&Abuf[cur][row][0] + boff);
#pragma unroll
            for (int g = 0; g < 3; ++g) {
                mfma16(acc[g][0], a, B[g][0][kk]);
                mfma16(acc[g][1], a, B[g][1][kk]);
            }
        }
#pragma unroll
        for (int q = 0; q < 2; ++q) {
            const int j = (w * 2 + q) * 16 + (lane & 15);
            f32x4 xr = *(const f32x4*)((const char*)&xpLs[cur][0] +
                        ((0 * 256 + j) * 16 + 4 * (lane >> 4)) * 4);
            f32x4 xz = *(const f32x4*)((const char*)&xpLs[cur][0] +
                        ((1 * 256 + j) * 16 + 4 * (lane >> 4)) * 4);
            f32x4 xn = *(const f32x4*)((const char*)&xpLs[cur][0] +
                        ((2 * 256 + j) * 16 + 4 * (lane >> 4)) * 4);
#pragma unroll
            for (int i = 0; i < 4; ++i) {
                const int b = 4 * (lane >> 4) + i;
                float rv = sigm(xr[i] + acc[0][q][i]);
                float zv = sigm(xz[i] + acc[1][q][i]);
                float nv = tanh_(xn[i] + rv * (acc[2][q][i] + bhn[q]));
                float hnew = (1.f - zv) * nv + zv * hreg[q][i];
                hreg[q][i] = hnew;
                unsigned short hb = f2bf(hnew);
                int byteoff = b * 512 + ((j * 2) ^ ((b & 7) << 4));
                *(unsigned short*)((char*)&Abuf[nxt][0][0] + byteoff) = hb;
                const int r2 = s * 32 + bh * 16 + b;
                const int hcol = dir * 256 + j;
                soFrag[(((r2 >> 4) * 16 + (hcol >> 5)) * 64 + (r2 & 15) +
                        ((hcol >> 3) & 3) * 16) * 8 + (hcol & 7)] = hb;
            }
        }
    }
}

// sentence softmax over S + pool + final linear (256 thr, k-split matmul)
__global__ void k_sent_pool_fin(const float* scoresS, const unsigned short* soFrag,
                                const float* finW, const float* finb, float* out)
{
    __shared__ float aL[16];
    __shared__ float pooled[512];
    __shared__ float part[4][64];
    const int l = threadIdx.x;   // 0..255
    const int b = blockIdx.x;    // 0..31

    if (l < 64) {
        float sc = (l < 16) ? scoresS[l * 32 + b] : -1e30f;
        float m = sc;
#pragma unroll
        for (int d = 1; d < 16; d <<= 1) m = fmaxf(m, __shfl_xor(m, d));
        float e = (l < 16) ? __expf(sc - m) : 0.f;
        float sum = e;
#pragma unroll
        for (int d = 1; d < 16; d <<= 1) sum += __shfl_xor(sum, d);
        if (l < 16) aL[l] = e * __builtin_amdgcn_rcpf(sum);
    }
    __syncthreads();

    if (l < 64) {
        float acc[8] = {};
        const i32x4* SO = (const i32x4*)soFrag;
        for (int si = 0; si < 16; ++si) {
            float as = aL[si];
            int r2 = si * 32 + b;
            int cidx = ((r2 >> 4) * 16 + (l >> 2)) * 64 + (r2 & 15) + (l & 3) * 16;
            i32x4 ch = SO[cidx];
            acc[0] += as * bf2f((unsigned short)((unsigned)ch.x & 0xffffu));
            acc[1] += as * bf2f((unsigned short)((unsigned)ch.x >> 16));
            acc[2] += as * bf2f((unsigned short)((unsigned)ch.y & 0xffffu));
            acc[3] += as * bf2f((unsigned short)((unsigned)ch.y >> 16));
            acc[4] += as * bf2f((unsigned short)((unsigned)ch.z & 0xffffu));
            acc[5] += as * bf2f((unsigned short)((unsigned)ch.z >> 16));
            acc[6] += as * bf2f((unsigned short)((unsigned)ch.w & 0xffffu));
            acc[7] += as * bf2f((unsigned short)((unsigned)ch.w >> 16));
        }
#pragma unroll
        for (int q = 0; q < 8; ++q) pooled[l * 8 + q] = acc[q];
    }
    __syncthreads();
    {
        const int c = l & 63, kq = l >> 6;
        float v = 0.f;
        if (c < 50) {
            const float* wrow = finW + c * 512 + kq * 128;
            const float* pp = pooled + kq * 128;
            for (int k = 0; k < 128; ++k) v += pp[k] * wrow[k];
        }
        part[kq][c] = v;
    }
    __syncthreads();
    if (l < 50)
        out[b * 50 + l] = finb[l] + part[0][l] + part[1][l] + part[2][l] + part[3][l];
}

// ---------------------------------------------------------------------------
extern "C" void kernel_launch(void* const* d_in, const int* in_sizes, int n_in,
                              void* d_out, int out_size, void* d_ws, size_t ws_size,
                              hipStream_t stream)
{
    if (ws_size < WS_NEED_B) return;
    const int bigA = (ws_size >= WS_NEED_A) ? 1 : 0;

    const int*   x      = (const int*)d_in[0];
    const float* embed  = (const float*)d_in[1];
    const float* wgWihF = (const float*)d_in[2];
    const float* wgWhhF = (const float*)d_in[3];
    const float* wgBihF = (const float*)d_in[4];
    const float* wgBhhF = (const float*)d_in[5];
    const float* wgWihB = (const float*)d_in[6];
    const float* wgWhhB = (const float*)d_in[7];
    const float* wgBihB = (const float*)d_in[8];
    const float* wgBhhB = (const float*)d_in[9];
    const float* wordW  = (const float*)d_in[10];
    const float* wordB  = (const float*)d_in[11];
    const float* wordP  = (const float*)d_in[12];
    const float* sgWihF = (const float*)d_in[13];
    const float* sgWhhF = (const float*)d_in[14];
    const float* sgBihF = (const float*)d_in[15];
    const float* sgBhhF = (const float*)d_in[16];
    const float* sgWihB = (const float*)d_in[17];
    const float* sgWhhB = (const float*)d_in[18];
    const float* sgBihB = (const float*)d_in[19];
    const float* sgBhhB = (const float*)d_in[20];
    const float* sentWm = (const float*)d_in[21];
    const float* sentB  = (const float*)d_in[22];
    const float* sentP  = (const float*)d_in[23];
    const float* finW   = (const float*)d_in[24];
    const float* finB   = (const float*)d_in[25];
    const float* stateW = (const float*)d_in[26];
    const float* stateS = (const float*)d_in[27];

    char* ws = (char*)d_ws;
    unsigned short* Wpwf   = (unsigned short*)(ws + O_WPWF);
    unsigned short* Wpwb   = (unsigned short*)(ws + O_WPWB);
    unsigned short* Wpsgih = (unsigned short*)(ws + O_WPSGIH);
    unsigned short* WpshhF = (unsigned short*)(ws + O_WPSHHF);
    unsigned short* WpshhB = (unsigned short*)(ws + O_WPSHHB);
    unsigned short* WpwW   = (unsigned short*)(ws + O_WPWW);
    unsigned short* WpsW   = (unsigned short*)(ws + O_WPSW);
    float* biasWf  = (float*)(ws + O_BIASWF);
    float* biasWb  = (float*)(ws + O_BIASWB);
    float* bihCat  = (float*)(ws + O_BIHCAT);
    unsigned short* wout   = (unsigned short*)(ws + O_WOUT);
    float* scoresW = (float*)(ws + O_SCORESW);
    unsigned short* ssFrag = (unsigned short*)(ws + O_SSFRAG);
    float* xpSent  = (float*)(ws + O_XPSENT);
    unsigned short* soFrag = (unsigned short*)(ws + O_SOFRAG);
    float* scoresS = (float*)(ws + O_SCORESS);
    unsigned short* xpw    = (unsigned short*)(ws + O_XPW);

    k_prep<<<512, 256, 0, stream>>>(wgWihF, wgWhhF, wgWihB, wgWhhB,
                                    sgWihF, sgWihB, sgWhhF, sgWhhB,
                                    wordW, sentWm,
                                    wgBihF, wgBhhF, wgBihB, wgBhhB,
                                    sgBihF, sgBihB, sgBhhF, sgBhhB,
                                    Wpwf, Wpwb, Wpsgih, WpshhF, WpshhB,
                                    WpwW, WpsW, biasWf, biasWb, bihCat);

    if (bigA) {
        k_xpw<<<256, 512, 0, stream>>>(x, embed, Wpwf, Wpwb, biasWf, biasWb, xpw);
        k_gru_wordA<<<64, 512, 0, stream>>>(stateW, Wpwf, Wpwb, biasWf, biasWb,
                                            xpw, wout);
    } else {
        k_gru_word<<<32, 1024, 0, stream>>>(x, embed, stateW, Wpwf, Wpwb,
                                            biasWf, biasWb, wout);
    }

    k_attn_score2<<<128, 1024, 0, stream>>>(wout, WpwW, wordB, wordP, scoresW);
    k_word_pool<<<512, 256, 0, stream>>>(scoresW, wout, ssFrag);

    k_sgih<<<dim3(32, 6), 256, 0, stream>>>(ssFrag, Wpsgih, bihCat, xpSent);
    k_gru_sentA<<<4, 512, 0, stream>>>(stateS, WpshhF, WpshhB, sgBhhF, sgBhhB,
                                       xpSent, soFrag);

    k_attn_score_small<<<8, 256, 0, stream>>>(soFrag, WpsW, sentB, sentP, scoresS);
    k_sent_pool_fin<<<32, 256, 0, stream>>>(scoresS, soFrag, finW, finB,
                                            (float*)d_out);
}